// Round 2
// 1882.243 us; speedup vs baseline: 1.1768x; 1.1768x over previous
//
#include <hip/hip_runtime.h>
#include <hip/hip_bf16.h>

#define VSZ   32000
#define DSZ   768
#define HN    12
#define HIDSZ 3072
#define NL    2
#define CN    2
#define RR    8
#define SCALEF 2.0f
#define BBATCH 64
#define SSEQ  512
#define HDIM  64
#define NTOK  (BBATCH*SSEQ)   // 32768
#define QKVM  (3*DSZ)         // 2304 — stacked QKV output width

typedef __attribute__((ext_vector_type(8))) short bf16x8;   // 8 bf16 (4 VGPRs)
typedef __attribute__((ext_vector_type(4))) float floatx4;

__device__ __forceinline__ unsigned short f2bf_raw(float f) {
    __hip_bfloat16 h = __float2bfloat16(f);
    return __builtin_bit_cast(unsigned short, h);
}
__device__ __forceinline__ float bf2f(__hip_bfloat16 h) {
    return __bfloat162float(h);
}

// ---------------------------------------------------------------------------
__device__ __forceinline__ void gload16(const void* g, void* l) {
    __builtin_amdgcn_global_load_lds(
        (const __attribute__((address_space(1))) unsigned int*)g,
        (__attribute__((address_space(3))) unsigned int*)l, 16, 0, 0);
}

// ---------------------------------------------------------------------------
// Embedding -> bf16 x
// ---------------------------------------------------------------------------
__global__ __launch_bounds__(256) void embed_kernel(
    const int* __restrict__ tokens, const float* __restrict__ embW,
    const float* __restrict__ embA, const float* __restrict__ embB,
    __hip_bfloat16* __restrict__ xb)
{
    int n = blockIdx.x;            // n = s*B + b
    int s = n / BBATCH, b = n % BBATCH;
    int tok = tokens[b * SSEQ + s];
    __shared__ float a[RR];
    if (threadIdx.x < RR) a[threadIdx.x] = embA[(size_t)threadIdx.x * VSZ + tok];
    __syncthreads();
    for (int d = threadIdx.x; d < DSZ; d += 256) {
        float val = embW[(size_t)tok * DSZ + d];
        float lo = 0.f;
        #pragma unroll
        for (int r = 0; r < RR; ++r) lo += a[r] * embB[d * RR + r];
        xb[(size_t)n * DSZ + d] = __float2bfloat16(val + SCALEF * lo);
    }
}

// ---------------------------------------------------------------------------
// Effective weight (LoRA folded) -> bf16.  grid = (K/256, M)
// ---------------------------------------------------------------------------
__global__ __launch_bounds__(256) void weff_kernel(
    const float* __restrict__ W, const float* __restrict__ A,
    const float* __restrict__ Bm, __hip_bfloat16* __restrict__ Weff, int K)
{
    int i = blockIdx.x * 256 + threadIdx.x;
    int o = blockIdx.y;
    float acc = W[(size_t)o * K + i];
    #pragma unroll
    for (int r = 0; r < RR; ++r)
        acc += SCALEF * Bm[o * RR + r] * A[(size_t)r * K + i];
    Weff[(size_t)o * K + i] = __float2bfloat16(acc);
}

__global__ __launch_bounds__(256) void biascat_kernel(
    const float* __restrict__ b0, const float* __restrict__ b1v,
    const float* __restrict__ b2v, float* __restrict__ out)
{
    int t = blockIdx.y * 256 + threadIdx.x;   // 0..767
    const float* src = (blockIdx.x == 0) ? b0 : (blockIdx.x == 1) ? b1v : b2v;
    out[blockIdx.x * DSZ + t] = src[t];
}

// ---------------------------------------------------------------------------
// 256x256 8-phase bf16 MFMA GEMM (T1+T2+T3+T4+T5).
// Y[n,m] = bf16( X@W^T + bias (+ res) ), optional relu.
// BK=64, 512 thr = 8 waves (2M x 4N); each tile-half is consumed in exactly
// ONE phase -> distance-2 same-buffer restaging is safe:
//   ph1: read A-h0+B-h0, stage A1(t+1) -> other buf     (A-h0/B-h0 done)
//   ph2: read B-h1,      stage A0(t+2) -> same buf      (B-h1 done)
//   ph3: read A-h1,      stage B0(t+2) -> same buf      (A-h1 done)
//   ph4: (regs held),    stage B1(t+2) -> same buf
//   boundary: vmcnt(6) (= 3 half-tiles * 2 loads in flight) BEFORE end barrier
// LDS: 2 dbuf x (A 32KB + B 32KB) = 128 KB, XOR-swizzled rows (pre-swizzled
// global source + swizzled ds_read: both-sides rule). Raw s_barrier only —
// no __syncthreads() (would drain vmcnt(0) and kill the pipeline).
// ---------------------------------------------------------------------------
#define BM2  256
#define BK2  64
#define ABUF (BM2*BK2)   // 16384 shorts = 32 KB

__device__ __forceinline__ void stage_half(
    const unsigned short* __restrict__ g, unsigned short* l,
    int h, int ld, int k0, int t, int sk)
{
    #pragma unroll
    for (int it = 0; it < 2; ++it) {
        int rl = it * 64 + (t >> 3);
        gload16(g + (size_t)(h * 128 + rl) * ld + k0 + sk,
                l + (size_t)(h * 1024 + it * 512 + t) * 8);
    }
}

__device__ __forceinline__ void ph_enter() {
    __builtin_amdgcn_sched_barrier(0);
    __builtin_amdgcn_s_barrier();
    asm volatile("s_waitcnt lgkmcnt(0)" ::: "memory");
    __builtin_amdgcn_sched_barrier(0);
    __builtin_amdgcn_s_setprio(1);
}

__device__ __forceinline__ void ph_exit() {
    __builtin_amdgcn_s_setprio(0);
    __builtin_amdgcn_sched_barrier(0);
    __builtin_amdgcn_s_barrier();
    __builtin_amdgcn_sched_barrier(0);
}

template<bool RELU, bool ADDRES>
__global__ __launch_bounds__(512, 2) void mgemm256_kernel(
    const __hip_bfloat16* __restrict__ X, const __hip_bfloat16* __restrict__ W,
    const float* __restrict__ bias, const __hip_bfloat16* __restrict__ res,
    __hip_bfloat16* __restrict__ Y, int K, int ldx, int ldy)
{
    __shared__ __align__(16) unsigned short As[2 * ABUF];   // 64 KB
    __shared__ __align__(16) unsigned short Bs[2 * ABUF];   // 64 KB

    const int t    = threadIdx.x;
    const int wv   = t >> 6;
    const int lane = t & 63;
    const int fm   = lane & 15;
    const int fq   = lane >> 4;
    const int wm   = wv >> 2;   // 0..1
    const int wn   = wv & 3;    // 0..3

    // T1: XCD-bijective block swizzle (8 XCDs)
    const int nbx = gridDim.x;
    int lin = blockIdx.y * nbx + blockIdx.x;
    {
        const int nwg = nbx * gridDim.y;
        int q = nwg >> 3, r = nwg & 7;
        int xcd = lin & 7, idx = lin >> 3;
        lin = (xcd < r ? xcd * (q + 1) : r * (q + 1) + (xcd - r) * q) + idx;
    }
    const int bm = lin % nbx;
    const int bn = lin / nbx;

    const unsigned short* Xg = (const unsigned short*)X + (size_t)bm * 256 * ldx;
    const unsigned short* Wg = (const unsigned short*)W + (size_t)bn * 256 * K;
    const int sk = ((t & 7) ^ ((t >> 3) & 7)) * 8;   // staging swizzle (elems)
    const int nt = K / BK2;

    floatx4 acc[2][2][4][2];
    #pragma unroll
    for (int a = 0; a < 2; ++a)
        #pragma unroll
        for (int b = 0; b < 2; ++b)
            #pragma unroll
            for (int c = 0; c < 4; ++c)
                #pragma unroll
                for (int d = 0; d < 2; ++d)
                    acc[a][b][c][d] = (floatx4){0.f, 0.f, 0.f, 0.f};

    // fragment base offsets (shorts), mh=0 / nh=0; +8192 for the other half,
    // ^32 for k-slice 1
    const int swzg = (fq ^ (fm & 7)) * 8;
    int aoff[4], boff[2];
    #pragma unroll
    for (int mf = 0; mf < 4; ++mf) aoff[mf] = (wm * 64 + mf * 16 + fm) * 64 + swzg;
    #pragma unroll
    for (int nf = 0; nf < 2; ++nf) boff[nf] = (wn * 32 + nf * 16 + fm) * 64 + swzg;

    // ---- prologue: tile0 full (A0,B0,A1,B1) + tile1 (A0,B0,B1) -> vmcnt(6)
    stage_half(Xg, As, 0, ldx, 0, t, sk);
    stage_half(Wg, Bs, 0, K,   0, t, sk);
    stage_half(Xg, As, 1, ldx, 0, t, sk);
    stage_half(Wg, Bs, 1, K,   0, t, sk);
    if (nt > 1) {
        stage_half(Xg, As + ABUF, 0, ldx, BK2, t, sk);
        stage_half(Wg, Bs + ABUF, 0, K,   BK2, t, sk);
        stage_half(Wg, Bs + ABUF, 1, K,   BK2, t, sk);
        asm volatile("s_waitcnt vmcnt(6)" ::: "memory");
    } else {
        asm volatile("s_waitcnt vmcnt(0)" ::: "memory");
    }
    __builtin_amdgcn_sched_barrier(0);
    __builtin_amdgcn_s_barrier();
    __builtin_amdgcn_sched_barrier(0);

    for (int kt = 0; kt < nt; ++kt) {
        const unsigned short* Ab = As + (kt & 1) * ABUF;
        const unsigned short* Bb = Bs + (kt & 1) * ABUF;
        unsigned short* Aoth  = As + ((kt & 1) ^ 1) * ABUF;
        unsigned short* Asame = (unsigned short*)Ab;
        unsigned short* Bsame = (unsigned short*)Bb;
        const int k1 = (kt + 1) * BK2;
        const int k2 = (kt + 2) * BK2;
        bf16x8 af[4][2], bf0[2][2], bf1[2][2];

        // ---- phase 1: A(mh0) + B(nh0); stage A1(kt+1) -> other buf
        #pragma unroll
        for (int mf = 0; mf < 4; ++mf) {
            af[mf][0] = *(const bf16x8*)&Ab[aoff[mf]];
            af[mf][1] = *(const bf16x8*)&Ab[aoff[mf] ^ 32];
        }
        #pragma unroll
        for (int nf = 0; nf < 2; ++nf) {
            bf0[nf][0] = *(const bf16x8*)&Bb[boff[nf]];
            bf0[nf][1] = *(const bf16x8*)&Bb[boff[nf] ^ 32];
        }
        if (kt + 1 < nt) stage_half(Xg, Aoth, 1, ldx, k1, t, sk);
        ph_enter();
        #pragma unroll
        for (int mf = 0; mf < 4; ++mf)
            #pragma unroll
            for (int nf = 0; nf < 2; ++nf) {
                acc[0][0][mf][nf] = __builtin_amdgcn_mfma_f32_16x16x32_bf16(
                    af[mf][0], bf0[nf][0], acc[0][0][mf][nf], 0, 0, 0);
                acc[0][0][mf][nf] = __builtin_amdgcn_mfma_f32_16x16x32_bf16(
                    af[mf][1], bf0[nf][1], acc[0][0][mf][nf], 0, 0, 0);
            }
        ph_exit();

        // ---- phase 2: B(nh1); stage A0(kt+2) -> same buf (A-h0 consumed @ph1)
        #pragma unroll
        for (int nf = 0; nf < 2; ++nf) {
            bf1[nf][0] = *(const bf16x8*)&Bb[(boff[nf] + 8192)];
            bf1[nf][1] = *(const bf16x8*)&Bb[(boff[nf] + 8192) ^ 32];
        }
        if (kt + 2 < nt) stage_half(Xg, Asame, 0, ldx, k2, t, sk);
        ph_enter();
        #pragma unroll
        for (int mf = 0; mf < 4; ++mf)
            #pragma unroll
            for (int nf = 0; nf < 2; ++nf) {
                acc[0][1][mf][nf] = __builtin_amdgcn_mfma_f32_16x16x32_bf16(
                    af[mf][0], bf1[nf][0], acc[0][1][mf][nf], 0, 0, 0);
                acc[0][1][mf][nf] = __builtin_amdgcn_mfma_f32_16x16x32_bf16(
                    af[mf][1], bf1[nf][1], acc[0][1][mf][nf], 0, 0, 0);
            }
        ph_exit();

        // ---- phase 3: A(mh1); stage B0(kt+2) -> same buf (B-h0 consumed @ph1)
        #pragma unroll
        for (int mf = 0; mf < 4; ++mf) {
            af[mf][0] = *(const bf16x8*)&Ab[(aoff[mf] + 8192)];
            af[mf][1] = *(const bf16x8*)&Ab[(aoff[mf] + 8192) ^ 32];
        }
        if (kt + 2 < nt) stage_half(Wg, Bsame, 0, K, k2, t, sk);
        ph_enter();
        #pragma unroll
        for (int mf = 0; mf < 4; ++mf)
            #pragma unroll
            for (int nf = 0; nf < 2; ++nf) {
                acc[1][0][mf][nf] = __builtin_amdgcn_mfma_f32_16x16x32_bf16(
                    af[mf][0], bf0[nf][0], acc[1][0][mf][nf], 0, 0, 0);
                acc[1][0][mf][nf] = __builtin_amdgcn_mfma_f32_16x16x32_bf16(
                    af[mf][1], bf0[nf][1], acc[1][0][mf][nf], 0, 0, 0);
            }
        ph_exit();

        // ---- phase 4: regs held; stage B1(kt+2) (B-h1 consumed @ph2);
        //      boundary vmcnt BEFORE the end barrier (cross-wave residency)
        if (kt + 2 < nt) stage_half(Wg, Bsame, 1, K, k2, t, sk);
        ph_enter();
        #pragma unroll
        for (int mf = 0; mf < 4; ++mf)
            #pragma unroll
            for (int nf = 0; nf < 2; ++nf) {
                acc[1][1][mf][nf] = __builtin_amdgcn_mfma_f32_16x16x32_bf16(
                    af[mf][0], bf1[nf][0], acc[1][1][mf][nf], 0, 0, 0);
                acc[1][1][mf][nf] = __builtin_amdgcn_mfma_f32_16x16x32_bf16(
                    af[mf][1], bf1[nf][1], acc[1][1][mf][nf], 0, 0, 0);
            }
        __builtin_amdgcn_s_setprio(0);
        __builtin_amdgcn_sched_barrier(0);
        if (kt + 2 < nt) {
            asm volatile("s_waitcnt vmcnt(6)" ::: "memory");
        } else if (kt + 1 < nt) {
            asm volatile("s_waitcnt vmcnt(0)" ::: "memory");
        }
        __builtin_amdgcn_sched_barrier(0);
        __builtin_amdgcn_s_barrier();
        __builtin_amdgcn_sched_barrier(0);
    }

    // ---- epilogue: row = bm*256 + mh*128 + wm*64 + mf*16 + fq*4 + r
    //               col = bn*256 + nh*128 + wn*32 + nf*16 + fm
    #pragma unroll
    for (int mh = 0; mh < 2; ++mh)
        #pragma unroll
        for (int nh = 0; nh < 2; ++nh)
            #pragma unroll
            for (int nf = 0; nf < 2; ++nf) {
                const int col = bn * 256 + nh * 128 + wn * 32 + nf * 16 + fm;
                const float bj = bias[col];
                #pragma unroll
                for (int mf = 0; mf < 4; ++mf) {
                    const int row0 = bm * 256 + mh * 128 + wm * 64 + mf * 16 + fq * 4;
                    #pragma unroll
                    for (int r = 0; r < 4; ++r) {
                        float v = acc[mh][nh][mf][nf][r] + bj;
                        if (RELU) v = fmaxf(v, 0.f);
                        size_t off = (size_t)(row0 + r) * ldy + col;
                        if (ADDRES) v += bf2f(res[off]);
                        Y[off] = __float2bfloat16(v);
                    }
                }
            }
}

// ---------------------------------------------------------------------------
// MFMA attention over the BATCH axis. qkvb bf16 rows stride QKVM: [Q|K|V].
// Block = one (s',h), 4 waves; wave w owns score rows 16w..16w+15.
// Output bf16 -> aob (stride DSZ). grid = schunk*HN.
// ---------------------------------------------------------------------------
__global__ __launch_bounds__(256) void attn_kernel(
    const __hip_bfloat16* __restrict__ qkvb, __hip_bfloat16* __restrict__ aob)
{
    __shared__ __align__(16) unsigned short Vt[64][72];      // Vt[d][c] = V[c][d]
    __shared__ __align__(16) unsigned short Ps[4][16][72];   // per-wave P rows
    const int t    = threadIdx.x;
    const int wv   = t >> 6;
    const int lane = t & 63;
    const int fm   = lane & 15;
    const int fq   = lane >> 4;
    const int sp   = blockIdx.x / HN;
    const int h    = blockIdx.x % HN;
    const unsigned short* qg =
        (const unsigned short*)qkvb + (size_t)sp * BBATCH * QKVM + h * HDIM;

    // ---- stage V transposed: thread (c=lane, d0=wv*16) reads V[c][d0..d0+15]
    {
        const int c = lane, d0 = wv * 16;
        const unsigned short* vrow = qg + 2 * DSZ + (size_t)c * QKVM + d0;
        bf16x8 v0 = *(const bf16x8*)vrow;
        bf16x8 v1 = *(const bf16x8*)(vrow + 8);
        #pragma unroll
        for (int i = 0; i < 8; ++i) {
            Vt[d0 + i][c]     = (unsigned short)v0[i];
            Vt[d0 + 8 + i][c] = (unsigned short)v1[i];
        }
    }

    // ---- Q A-frags (own 16 rows) and K B-frags (all 64 cols), direct global
    const unsigned short* qrow = qg + (size_t)(wv * 16 + fm) * QKVM + fq * 8;
    bf16x8 af0 = *(const bf16x8*)qrow;
    bf16x8 af1 = *(const bf16x8*)(qrow + 32);
    bf16x8 bk0[4], bk1[4];
    #pragma unroll
    for (int jt = 0; jt < 4; ++jt) {
        const unsigned short* krow = qg + DSZ + (size_t)(jt * 16 + fm) * QKVM + fq * 8;
        bk0[jt] = *(const bf16x8*)krow;
        bk1[jt] = *(const bf16x8*)(krow + 32);
    }

    // ---- scores: 16x64 per wave, fp32 acc
    floatx4 sc[4];
    #pragma unroll
    for (int jt = 0; jt < 4; ++jt) sc[jt] = (floatx4){0.f, 0.f, 0.f, 0.f};
    #pragma unroll
    for (int jt = 0; jt < 4; ++jt) {
        sc[jt] = __builtin_amdgcn_mfma_f32_16x16x32_bf16(af0, bk0[jt], sc[jt], 0, 0, 0);
        sc[jt] = __builtin_amdgcn_mfma_f32_16x16x32_bf16(af1, bk1[jt], sc[jt], 0, 0, 0);
    }
    #pragma unroll
    for (int jt = 0; jt < 4; ++jt)
        #pragma unroll
        for (int r = 0; r < 4; ++r) sc[jt][r] *= 0.125f;

    // ---- softmax per row (row = fq*4+r, spread over 16 lanes x 4 jt)
    float pr[4][4];
    #pragma unroll
    for (int r = 0; r < 4; ++r) {
        float m = fmaxf(fmaxf(sc[0][r], sc[1][r]), fmaxf(sc[2][r], sc[3][r]));
        #pragma unroll
        for (int msk = 1; msk < 16; msk <<= 1) m = fmaxf(m, __shfl_xor(m, msk, 64));
        float s = 0.f;
        #pragma unroll
        for (int jt = 0; jt < 4; ++jt) { pr[jt][r] = __expf(sc[jt][r] - m); s += pr[jt][r]; }
        #pragma unroll
        for (int msk = 1; msk < 16; msk <<= 1) s += __shfl_xor(s, msk, 64);
        float inv = 1.f / s;
        #pragma unroll
        for (int jt = 0; jt < 4; ++jt) pr[jt][r] *= inv;
    }

    // ---- P -> LDS (C-layout -> A-layout round trip), bf16
    #pragma unroll
    for (int jt = 0; jt < 4; ++jt)
        #pragma unroll
        for (int r = 0; r < 4; ++r)
            Ps[wv][fq * 4 + r][jt * 16 + fm] = f2bf_raw(pr[jt][r]);

    __syncthreads();   // Vt (cross-wave) ready; Ps is wave-local

    // ---- PV: A = P (own rows), B = Vt
    bf16x8 ap0 = *(const bf16x8*)&Ps[wv][fm][fq * 8];
    bf16x8 ap1 = *(const bf16x8*)&Ps[wv][fm][32 + fq * 8];
    floatx4 ov[4];
    #pragma unroll
    for (int jt = 0; jt < 4; ++jt) ov[jt] = (floatx4){0.f, 0.f, 0.f, 0.f};
    #pragma unroll
    for (int jt = 0; jt < 4; ++jt) {
        bf16x8 bv0 = *(const bf16x8*)&Vt[jt * 16 + fm][fq * 8];
        bf16x8 bv1 = *(const bf16x8*)&Vt[jt * 16 + fm][32 + fq * 8];
        ov[jt] = __builtin_amdgcn_mfma_f32_16x16x32_bf16(ap0, bv0, ov[jt], 0, 0, 0);
        ov[jt] = __builtin_amdgcn_mfma_f32_16x16x32_bf16(ap1, bv1, ov[jt], 0, 0, 0);
    }

    // ---- write O bf16: row b = 16wv + 4fq + r, col d = jt*16+fm
    __hip_bfloat16* obase = aob + ((size_t)sp * BBATCH + wv * 16 + fq * 4) * DSZ + h * HDIM;
    #pragma unroll
    for (int jt = 0; jt < 4; ++jt)
        #pragma unroll
        for (int r = 0; r < 4; ++r)
            obase[(size_t)r * DSZ + jt * 16 + fm] = __float2bfloat16(ov[jt][r]);
}

// ---------------------------------------------------------------------------
// LayerNorm: src bf16 -> dst bf16 (separate buffers), fp32 stats.
// ---------------------------------------------------------------------------
__device__ __forceinline__ float block_sum256(float vsum, volatile float* red) {
    #pragma unroll
    for (int off = 32; off > 0; off >>= 1) vsum += __shfl_down(vsum, off, 64);
    if ((threadIdx.x & 63) == 0) red[threadIdx.x >> 6] = vsum;
    __syncthreads();
    return red[0] + red[1] + red[2] + red[3];
}

__global__ __launch_bounds__(256) void ln_kernel(
    const __hip_bfloat16* __restrict__ src, __hip_bfloat16* __restrict__ dst,
    const float* __restrict__ g, const float* __restrict__ be)
{
    __shared__ float red1[4];
    __shared__ float red2[4];
    const int n = blockIdx.x;
    const int t = threadIdx.x;
    const __hip_bfloat16* row = src + (size_t)n * DSZ;
    __hip_bfloat16* orow = dst + (size_t)n * DSZ;
    float v0 = bf2f(row[t]), v1 = bf2f(row[t + 256]), v2 = bf2f(row[t + 512]);
    float total = block_sum256(v0 + v1 + v2, red1);
    float mean = total * (1.0f / DSZ);
    float d0 = v0 - mean, d1 = v1 - mean, d2 = v2 - mean;
    __syncthreads();
    float var = block_sum256(d0 * d0 + d1 * d1 + d2 * d2, red2) * (1.0f / DSZ);
    float rstd = rsqrtf(var + 1e-5f);
    orow[t]       = __float2bfloat16(d0 * rstd * g[t]       + be[t]);
    orow[t + 256] = __float2bfloat16(d1 * rstd * g[t + 256] + be[t + 256]);
    orow[t + 512] = __float2bfloat16(d2 * rstd * g[t + 512] + be[t + 512]);
}

// ---------------------------------------------------------------------------
__global__ __launch_bounds__(256) void meanS_kernel(
    const __hip_bfloat16* __restrict__ x, float* __restrict__ xm)
{
    int idx = blockIdx.x * 256 + threadIdx.x;   // over B*D, d fastest
    int b = idx / DSZ, d = idx % DSZ;
    float acc = 0.f;
    for (int s = 0; s < SSEQ; ++s)
        acc += bf2f(x[((size_t)s * BBATCH + b) * DSZ + d]);
    xm[idx] = acc * (1.0f / SSEQ);
}

__global__ __launch_bounds__(128) void fc_kernel(
    const float* __restrict__ xm, const float* __restrict__ fcW,
    const float* __restrict__ fcb, const float* __restrict__ fcA,
    const float* __restrict__ fcBm, float* __restrict__ out)
{
    int t = threadIdx.x;
    if (t >= BBATCH * CN) return;
    int b = t / CN, c = t % CN;
    float acc = fcb[c];
    float lora[RR];
    #pragma unroll
    for (int r = 0; r < RR; ++r) lora[r] = 0.f;
    for (int d = 0; d < DSZ; ++d) {
        float xv = xm[b * DSZ + d];
        acc += xv * fcW[c * DSZ + d];
        #pragma unroll
        for (int r = 0; r < RR; ++r) lora[r] += xv * fcA[r * DSZ + d];
    }
    float lo = 0.f;
    #pragma unroll
    for (int r = 0; r < RR; ++r) lo += lora[r] * fcBm[c * RR + r];
    out[b * CN + c] = acc + SCALEF * lo;
}

// ---------------------------------------------------------------------------
extern "C" void kernel_launch(void* const* d_in, const int* in_sizes, int n_in,
                              void* d_out, int out_size, void* d_ws, size_t ws_size,
                              hipStream_t stream) {
    const int*   tokens = (const int*)  d_in[0];
    const float* embW   = (const float*)d_in[1];
    const float* embA   = (const float*)d_in[2];
    const float* embB   = (const float*)d_in[3];
    const float* Wq = (const float*)d_in[4],  *bq = (const float*)d_in[5],
               * Aq = (const float*)d_in[6],  *Bq = (const float*)d_in[7];
    const float* Wk = (const float*)d_in[8],  *bk = (const float*)d_in[9],
               * Ak = (const float*)d_in[10], *Bk = (const float*)d_in[11];
    const float* Wv = (const float*)d_in[12], *bv = (const float*)d_in[13],
               * Av = (const float*)d_in[14], *Bv = (const float*)d_in[15];
    const float* Wo = (const float*)d_in[16], *bo = (const float*)d_in[17],
               * Ao = (const float*)d_in[18], *Bo = (const float*)d_in[19];
    const float* W1 = (const float*)d_in[20], *b1 = (const float*)d_in[21],
               * A1 = (const float*)d_in[22], *B1 = (const float*)d_in[23];
    const float* W2 = (const float*)d_in[24], *b2 = (const float*)d_in[25],
               * A2 = (const float*)d_in[26], *B2 = (const float*)d_in[27];
    const float* g1 = (const float*)d_in[28], *be1 = (const float*)d_in[29];
    const float* g2 = (const float*)d_in[30], *be2 = (const float*)d_in[31];
    const float* fcW = (const float*)d_in[32], *fcb = (const float*)d_in[33];
    const float* fcA = (const float*)d_in[34], *fcBm = (const float*)d_in[35];

    const size_t ND = (size_t)NTOK * DSZ;

    // ---- workspace layout (float units; all sections multiple of 4) ------
    const size_t X_F    = ND / 2;                       // bf16 x (LN out / residual base)
    const size_t XT_F   = ND / 2;                       // bf16 xt (pre-LN sum)
    const size_t WQKV_F = (size_t)QKVM * DSZ / 2;
    const size_t WO_F   = (size_t)DSZ * DSZ / 2;
    const size_t WF1_F  = (size_t)HIDSZ * DSZ / 2;
    const size_t WF2_F  = (size_t)DSZ * HIDSZ / 2;
    const size_t BQKV_F = 2304;
    const size_t XM_F   = (size_t)BBATCH * DSZ;
    const size_t fixedF = X_F + XT_F + WQKV_F + WO_F + WF1_F + WF2_F + BQKV_F + XM_F;
    const size_t availF = ws_size / 4;

    int schunk = 2;
    const int cand[6] = {512, 256, 128, 64, 32, 16};
    for (int i = 0; i < 6; ++i) {
        // per-chunk: bf16 qkv (Nc*2304) + bf16 aob (Nc*768) == bf16 h (Nc*3072)
        size_t chunkF = (size_t)cand[i] * BBATCH * (HIDSZ / 2);
        if (fixedF + chunkF <= availF) { schunk = cand[i]; break; }
    }
    const int Nc = schunk * BBATCH;
    const int nchunk = SSEQ / schunk;

    float* p = (float*)d_ws;
    __hip_bfloat16* x  = (__hip_bfloat16*)p;     p += X_F;
    __hip_bfloat16* xt = (__hip_bfloat16*)p;     p += XT_F;
    __hip_bfloat16* wqkvb = (__hip_bfloat16*)p;  p += WQKV_F;
    __hip_bfloat16* wob   = (__hip_bfloat16*)p;  p += WO_F;
    __hip_bfloat16* wf1b  = (__hip_bfloat16*)p;  p += WF1_F;
    __hip_bfloat16* wf2b  = (__hip_bfloat16*)p;  p += WF2_F;
    float* bqkv = p;                             p += BQKV_F;
    float* xm   = p;                             p += XM_F;
    __hip_bfloat16* cb16 = (__hip_bfloat16*)p;   // chunk: qkvb|aob, later h
    __hip_bfloat16* qkvb = cb16;
    __hip_bfloat16* aob  = cb16 + (size_t)Nc * QKVM;
    __hip_bfloat16* hb   = cb16;

    embed_kernel<<<NTOK, 256, 0, stream>>>(tokens, embW, embA, embB, x);

    for (int l = 0; l < NL; ++l) {
        const size_t oDD = (size_t)l * DSZ * DSZ;
        const size_t oDH = (size_t)l * HIDSZ * DSZ;
        const size_t oRD = (size_t)l * RR * DSZ;
        const size_t oRH = (size_t)l * RR * HIDSZ;
        const size_t oDR = (size_t)l * DSZ * RR;
        const size_t oHR = (size_t)l * HIDSZ * RR;

        weff_kernel<<<dim3(3, DSZ), 256, 0, stream>>>(Wq + oDD, Aq + oRD, Bq + oDR, wqkvb, DSZ);
        weff_kernel<<<dim3(3, DSZ), 256, 0, stream>>>(Wk + oDD, Ak + oRD, Bk + oDR, wqkvb + (size_t)DSZ * DSZ, DSZ);
        weff_kernel<<<dim3(3, DSZ), 256, 0, stream>>>(Wv + oDD, Av + oRD, Bv + oDR, wqkvb + (size_t)2 * DSZ * DSZ, DSZ);
        biascat_kernel<<<dim3(3, 3), 256, 0, stream>>>(bq + (size_t)l * DSZ, bk + (size_t)l * DSZ, bv + (size_t)l * DSZ, bqkv);
        weff_kernel<<<dim3(3, DSZ), 256, 0, stream>>>(Wo + oDD, Ao + oRD, Bo + oDR, wob, DSZ);
        weff_kernel<<<dim3(3, HIDSZ), 256, 0, stream>>>(W1 + oDH, A1 + oRD, B1 + oHR, wf1b, DSZ);
        weff_kernel<<<dim3(12, DSZ), 256, 0, stream>>>(W2 + oDH, A2 + oRH, B2 + oDR, wf2b, HIDSZ);

        const float* bo_l = bo + (size_t)l * DSZ;
        const float* b1_l = b1 + (size_t)l * HIDSZ;
        const float* b2_l = b2 + (size_t)l * DSZ;

        for (int c = 0; c < nchunk; ++c) {
            __hip_bfloat16* xc  = x  + (size_t)c * Nc * DSZ;
            __hip_bfloat16* xtc = xt + (size_t)c * Nc * DSZ;

            // QKV stacked: (Nc x 768) @ (2304 x 768)^T -> bf16 qkvb
            mgemm256_kernel<false, false><<<dim3(Nc / BM2, QKVM / BM2), 512, 0, stream>>>(
                xc, wqkvb, bqkv, nullptr, qkvb, DSZ, DSZ, QKVM);

            attn_kernel<<<schunk * HN, 256, 0, stream>>>(qkvb, aob);

            // O-proj + residual(x) -> xt, then LN1: xt -> x
            mgemm256_kernel<false, true><<<dim3(Nc / BM2, DSZ / BM2), 512, 0, stream>>>(
                aob, wob, bo_l, xc, xtc, DSZ, DSZ, DSZ);
            ln_kernel<<<Nc, 256, 0, stream>>>(xtc, xc, g1 + (size_t)l * DSZ, be1 + (size_t)l * DSZ);

            // FF1 (relu) -> bf16 h (qkv/aob dead, reuse chunk buffer)
            mgemm256_kernel<true, false><<<dim3(Nc / BM2, HIDSZ / BM2), 512, 0, stream>>>(
                xc, wf1b, b1_l, nullptr, hb, DSZ, DSZ, HIDSZ);

            // FF2 + residual(x) -> xt, then LN2: xt -> x
            mgemm256_kernel<false, true><<<dim3(Nc / BM2, DSZ / BM2), 512, 0, stream>>>(
                hb, wf2b, b2_l, xc, xtc, HIDSZ, HIDSZ, DSZ);
            ln_kernel<<<Nc, 256, 0, stream>>>(xtc, xc, g2 + (size_t)l * DSZ, be2 + (size_t)l * DSZ);
        }
    }

    meanS_kernel<<<(BBATCH * DSZ) / 256, 256, 0, stream>>>(x, xm);
    fc_kernel<<<1, 128, 0, stream>>>(xm, fcW, fcb, fcA, fcBm, (float*)d_out);
}

// Round 3
// 1855.956 us; speedup vs baseline: 1.1935x; 1.0142x over previous
//
#include <hip/hip_runtime.h>
#include <hip/hip_bf16.h>

#define VSZ   32000
#define DSZ   768
#define HN    12
#define HIDSZ 3072
#define NL    2
#define CN    2
#define RR    8
#define SCALEF 2.0f
#define BBATCH 64
#define SSEQ  512
#define HDIM  64
#define NTOK  (BBATCH*SSEQ)   // 32768
#define QKVM  (3*DSZ)         // 2304 — stacked QKV output width

typedef __attribute__((ext_vector_type(8))) short bf16x8;   // 8 bf16 (4 VGPRs)
typedef __attribute__((ext_vector_type(4))) float floatx4;

__device__ __forceinline__ unsigned short f2bf_raw(float f) {
    __hip_bfloat16 h = __float2bfloat16(f);
    return __builtin_bit_cast(unsigned short, h);
}
__device__ __forceinline__ float bf2f(__hip_bfloat16 h) {
    return __bfloat162float(h);
}

// ---------------------------------------------------------------------------
__device__ __forceinline__ void gload16(const void* g, void* l) {
    __builtin_amdgcn_global_load_lds(
        (const __attribute__((address_space(1))) unsigned int*)g,
        (__attribute__((address_space(3))) unsigned int*)l, 16, 0, 0);
}

// ---------------------------------------------------------------------------
// Embedding -> bf16 x
// ---------------------------------------------------------------------------
__global__ __launch_bounds__(256) void embed_kernel(
    const int* __restrict__ tokens, const float* __restrict__ embW,
    const float* __restrict__ embA, const float* __restrict__ embB,
    __hip_bfloat16* __restrict__ xb)
{
    int n = blockIdx.x;            // n = s*B + b
    int s = n / BBATCH, b = n % BBATCH;
    int tok = tokens[b * SSEQ + s];
    __shared__ float a[RR];
    if (threadIdx.x < RR) a[threadIdx.x] = embA[(size_t)threadIdx.x * VSZ + tok];
    __syncthreads();
    for (int d = threadIdx.x; d < DSZ; d += 256) {
        float val = embW[(size_t)tok * DSZ + d];
        float lo = 0.f;
        #pragma unroll
        for (int r = 0; r < RR; ++r) lo += a[r] * embB[d * RR + r];
        xb[(size_t)n * DSZ + d] = __float2bfloat16(val + SCALEF * lo);
    }
}

// ---------------------------------------------------------------------------
// Effective weight (LoRA folded) -> bf16.  grid = (K/256, M)
// ---------------------------------------------------------------------------
__global__ __launch_bounds__(256) void weff_kernel(
    const float* __restrict__ W, const float* __restrict__ A,
    const float* __restrict__ Bm, __hip_bfloat16* __restrict__ Weff, int K)
{
    int i = blockIdx.x * 256 + threadIdx.x;
    int o = blockIdx.y;
    float acc = W[(size_t)o * K + i];
    #pragma unroll
    for (int r = 0; r < RR; ++r)
        acc += SCALEF * Bm[o * RR + r] * A[(size_t)r * K + i];
    Weff[(size_t)o * K + i] = __float2bfloat16(acc);
}

__global__ __launch_bounds__(256) void biascat_kernel(
    const float* __restrict__ b0, const float* __restrict__ b1v,
    const float* __restrict__ b2v, float* __restrict__ out)
{
    int t = blockIdx.y * 256 + threadIdx.x;   // 0..767
    const float* src = (blockIdx.x == 0) ? b0 : (blockIdx.x == 1) ? b1v : b2v;
    out[blockIdx.x * DSZ + t] = src[t];
}

// ---------------------------------------------------------------------------
// 256x256 8-phase bf16 MFMA GEMM, software-pipelined LDS reads.
// Y[n,m] = bf16( X@W^T + bias (+ res) ), optional relu.
// BK=64, 512 thr = 8 waves (2M x 4N). Per kt, 4 phases; each gap issues the
// NEXT phase's ds_reads so the LDS pipe drains DURING the MFMA segment
// (counted lgkmcnt completes only the older read group):
//   gap1: issue bf1(kt);            stage A1(kt+1)->Ob  | ph1 lgkm(4): af0 x bf0
//   gap2: issue af1(kt);            stage A0(kt+2)->Ab  | ph2 lgkm(8): af0 x bf1
//   gap3:                           stage B0(kt+2)->Ab  | ph3 lgkm(0): af1 x bf0
//   gap4: vmcnt(4); issue af0,bf0(kt+1) from Ob;
//                                   stage B1(kt+2)->Ab  | ph4 (no wait): af1 x bf1
// Residency ledger: entry outstanding = 6 loads {A0,B0,B1}(kt+1); gap4's
// vmcnt(4) completes {entry-6, A1(kt+1)} -> all prefetch sources landed.
// Every staged-over region is fully read + lgkm'd + barrier-separated before
// its overwrite issues (re-derived per region). Tail: end-of-iter vmcnt(0)
// when kt+1==nt-1 guarantees the last tile is resident for gap1/gap2 reads.
// LDS: 2 dbuf x 32KB x {A,B} = 128 KB, XOR-swizzled (pre-swizzled global src
// + swizzled ds_read). Raw s_barrier only; sched_barrier(0) fences per rule 18.
// Grid: bn-fastest (consecutive blocks share the X panel -> L2 reuse) with
// bijective XCD chunking.
// ---------------------------------------------------------------------------
#define BM2  256
#define BK2  64
#define ABUF (BM2*BK2)   // 16384 shorts = 32 KB

#define SB0() __builtin_amdgcn_sched_barrier(0)

__device__ __forceinline__ void stage_half(
    const unsigned short* __restrict__ g, unsigned short* l,
    int h, int ld, int k0, int t, int sk)
{
    #pragma unroll
    for (int it = 0; it < 2; ++it) {
        int rl = it * 64 + (t >> 3);
        gload16(g + (size_t)(h * 128 + rl) * ld + k0 + sk,
                l + (size_t)(h * 1024 + it * 512 + t) * 8);
    }
}

__device__ __forceinline__ void ph_exit() {
    __builtin_amdgcn_s_setprio(0);
    SB0();
    __builtin_amdgcn_s_barrier();
    SB0();
}

template<bool RELU, bool ADDRES>
__global__ __launch_bounds__(512, 2) void mgemm256_kernel(
    const __hip_bfloat16* __restrict__ X, const __hip_bfloat16* __restrict__ W,
    const float* __restrict__ bias, const __hip_bfloat16* __restrict__ res,
    __hip_bfloat16* __restrict__ Y, int K, int ldx, int ldy)
{
    __shared__ __align__(16) unsigned short As[2 * ABUF];   // 64 KB
    __shared__ __align__(16) unsigned short Bs[2 * ABUF];   // 64 KB

    const int t    = threadIdx.x;
    const int wv   = t >> 6;
    const int lane = t & 63;
    const int fm   = lane & 15;
    const int fq   = lane >> 4;
    const int wm   = wv >> 2;   // 0..1
    const int wn   = wv & 3;    // 0..3

    // T1: XCD-bijective block swizzle (8 XCDs), then bn-fastest decode
    const int nbx = gridDim.x;   // M blocks
    const int nby = gridDim.y;   // N blocks
    int lin = blockIdx.y * nbx + blockIdx.x;
    {
        const int nwg = nbx * nby;
        int q = nwg >> 3, r = nwg & 7;
        int xcd = lin & 7, idx = lin >> 3;
        lin = (xcd < r ? xcd * (q + 1) : r * (q + 1) + (xcd - r) * q) + idx;
    }
    const int bn = lin % nby;    // N fastest: consecutive blocks share X panel
    const int bm = lin / nby;

    const unsigned short* Xg = (const unsigned short*)X + (size_t)bm * 256 * ldx;
    const unsigned short* Wg = (const unsigned short*)W + (size_t)bn * 256 * K;
    const int sk = ((t & 7) ^ ((t >> 3) & 7)) * 8;   // staging swizzle (elems)
    const int nt = K / BK2;

    floatx4 acc[2][2][4][2];
    #pragma unroll
    for (int a = 0; a < 2; ++a)
        #pragma unroll
        for (int b = 0; b < 2; ++b)
            #pragma unroll
            for (int c = 0; c < 4; ++c)
                #pragma unroll
                for (int d = 0; d < 2; ++d)
                    acc[a][b][c][d] = (floatx4){0.f, 0.f, 0.f, 0.f};

    // fragment base offsets (shorts), h0; +8192 for h1, ^32 for k-slice 1
    const int swzg = (fq ^ (fm & 7)) * 8;
    int aoff[4], boff[2];
    #pragma unroll
    for (int mf = 0; mf < 4; ++mf) aoff[mf] = (wm * 64 + mf * 16 + fm) * 64 + swzg;
    #pragma unroll
    for (int nf = 0; nf < 2; ++nf) boff[nf] = (wn * 32 + nf * 16 + fm) * 64 + swzg;

    // ---- prologue: tile0 full (A0,B0,A1,B1) + tile1 (A0,B0,B1) -> vmcnt(6)
    stage_half(Xg, As, 0, ldx, 0, t, sk);
    stage_half(Wg, Bs, 0, K,   0, t, sk);
    stage_half(Xg, As, 1, ldx, 0, t, sk);
    stage_half(Wg, Bs, 1, K,   0, t, sk);
    if (nt > 1) {
        stage_half(Xg, As + ABUF, 0, ldx, BK2, t, sk);
        stage_half(Wg, Bs + ABUF, 0, K,   BK2, t, sk);
        stage_half(Wg, Bs + ABUF, 1, K,   BK2, t, sk);
        asm volatile("s_waitcnt vmcnt(6)" ::: "memory");
    } else {
        asm volatile("s_waitcnt vmcnt(0)" ::: "memory");
    }
    SB0();
    __builtin_amdgcn_s_barrier();
    SB0();

    // pre-issue ph1(kt=0) reads: af0 (A h0), bf0 (B h0) from buffer 0
    bf16x8 af0[4][2], af1[4][2], bf0[2][2], bf1[2][2];
    #pragma unroll
    for (int mf = 0; mf < 4; ++mf) {
        af0[mf][0] = *(const bf16x8*)&As[aoff[mf]];
        af0[mf][1] = *(const bf16x8*)&As[aoff[mf] ^ 32];
    }
    #pragma unroll
    for (int nf = 0; nf < 2; ++nf) {
        bf0[nf][0] = *(const bf16x8*)&Bs[boff[nf]];
        bf0[nf][1] = *(const bf16x8*)&Bs[boff[nf] ^ 32];
    }
    SB0();

    for (int kt = 0; kt < nt; ++kt) {
        const unsigned short* Ab = As + (kt & 1) * ABUF;
        const unsigned short* Bb = Bs + (kt & 1) * ABUF;
        unsigned short* AobW = As + ((kt & 1) ^ 1) * ABUF;
        const unsigned short* AobR = AobW;
        const unsigned short* BobR = Bs + ((kt & 1) ^ 1) * ABUF;
        unsigned short* Asame = (unsigned short*)Ab;
        unsigned short* Bsame = (unsigned short*)Bb;
        const int k1 = (kt + 1) * BK2;
        const int k2 = (kt + 2) * BK2;

        // ---- gap1: issue bf1(kt) reads; stage A1(kt+1) -> other buf
        #pragma unroll
        for (int nf = 0; nf < 2; ++nf) {
            bf1[nf][0] = *(const bf16x8*)&Bb[(boff[nf] + 8192)];
            bf1[nf][1] = *(const bf16x8*)&Bb[(boff[nf] + 8192) ^ 32];
        }
        SB0();
        if (kt + 1 < nt) stage_half(Xg, AobW, 1, ldx, k1, t, sk);
        SB0();
        __builtin_amdgcn_s_barrier();
        asm volatile("s_waitcnt lgkmcnt(4)" ::: "memory");   // af0,bf0 done
        SB0();
        __builtin_amdgcn_s_setprio(1);
        #pragma unroll
        for (int mf = 0; mf < 4; ++mf)
            #pragma unroll
            for (int nf = 0; nf < 2; ++nf) {
                acc[0][0][mf][nf] = __builtin_amdgcn_mfma_f32_16x16x32_bf16(
                    af0[mf][0], bf0[nf][0], acc[0][0][mf][nf], 0, 0, 0);
                acc[0][0][mf][nf] = __builtin_amdgcn_mfma_f32_16x16x32_bf16(
                    af0[mf][1], bf0[nf][1], acc[0][0][mf][nf], 0, 0, 0);
            }
        ph_exit();

        // ---- gap2: issue af1(kt) reads; stage A0(kt+2) -> same buf
        #pragma unroll
        for (int mf = 0; mf < 4; ++mf) {
            af1[mf][0] = *(const bf16x8*)&Ab[(aoff[mf] + 8192)];
            af1[mf][1] = *(const bf16x8*)&Ab[(aoff[mf] + 8192) ^ 32];
        }
        SB0();
        if (kt + 2 < nt) stage_half(Xg, Asame, 0, ldx, k2, t, sk);
        SB0();
        __builtin_amdgcn_s_barrier();
        asm volatile("s_waitcnt lgkmcnt(8)" ::: "memory");   // bf1 done
        SB0();
        __builtin_amdgcn_s_setprio(1);
        #pragma unroll
        for (int mf = 0; mf < 4; ++mf)
            #pragma unroll
            for (int nf = 0; nf < 2; ++nf) {
                acc[0][1][mf][nf] = __builtin_amdgcn_mfma_f32_16x16x32_bf16(
                    af0[mf][0], bf1[nf][0], acc[0][1][mf][nf], 0, 0, 0);
                acc[0][1][mf][nf] = __builtin_amdgcn_mfma_f32_16x16x32_bf16(
                    af0[mf][1], bf1[nf][1], acc[0][1][mf][nf], 0, 0, 0);
            }
        ph_exit();

        // ---- gap3: stage B0(kt+2) -> same buf
        if (kt + 2 < nt) stage_half(Wg, Bsame, 0, K, k2, t, sk);
        SB0();
        __builtin_amdgcn_s_barrier();
        asm volatile("s_waitcnt lgkmcnt(0)" ::: "memory");   // af1 done
        SB0();
        __builtin_amdgcn_s_setprio(1);
        #pragma unroll
        for (int mf = 0; mf < 4; ++mf)
            #pragma unroll
            for (int nf = 0; nf < 2; ++nf) {
                acc[1][0][mf][nf] = __builtin_amdgcn_mfma_f32_16x16x32_bf16(
                    af1[mf][0], bf0[nf][0], acc[1][0][mf][nf], 0, 0, 0);
                acc[1][0][mf][nf] = __builtin_amdgcn_mfma_f32_16x16x32_bf16(
                    af1[mf][1], bf0[nf][1], acc[1][0][mf][nf], 0, 0, 0);
            }
        ph_exit();

        // ---- gap4: vmcnt(4) (other buf h0 landed); prefetch af0,bf0(kt+1);
        //            stage B1(kt+2) -> same buf
        asm volatile("s_waitcnt vmcnt(4)" ::: "memory");
        SB0();
        if (kt + 1 < nt) {
            #pragma unroll
            for (int mf = 0; mf < 4; ++mf) {
                af0[mf][0] = *(const bf16x8*)&AobR[aoff[mf]];
                af0[mf][1] = *(const bf16x8*)&AobR[aoff[mf] ^ 32];
            }
            #pragma unroll
            for (int nf = 0; nf < 2; ++nf) {
                bf0[nf][0] = *(const bf16x8*)&BobR[boff[nf]];
                bf0[nf][1] = *(const bf16x8*)&BobR[boff[nf] ^ 32];
            }
        }
        SB0();
        if (kt + 2 < nt) stage_half(Wg, Bsame, 1, K, k2, t, sk);
        SB0();
        __builtin_amdgcn_s_barrier();
        SB0();                                   // ph4 operands already complete
        __builtin_amdgcn_s_setprio(1);
        #pragma unroll
        for (int mf = 0; mf < 4; ++mf)
            #pragma unroll
            for (int nf = 0; nf < 2; ++nf) {
                acc[1][1][mf][nf] = __builtin_amdgcn_mfma_f32_16x16x32_bf16(
                    af1[mf][0], bf1[nf][0], acc[1][1][mf][nf], 0, 0, 0);
                acc[1][1][mf][nf] = __builtin_amdgcn_mfma_f32_16x16x32_bf16(
                    af1[mf][1], bf1[nf][1], acc[1][1][mf][nf], 0, 0, 0);
            }
        __builtin_amdgcn_s_setprio(0);
        SB0();
        if (kt + 2 < nt) {
            asm volatile("s_waitcnt vmcnt(6)" ::: "memory");   // steady no-op guard
        } else if (kt + 1 < nt) {
            asm volatile("s_waitcnt vmcnt(0)" ::: "memory");   // last tile resident
        }
        SB0();
        __builtin_amdgcn_s_barrier();
        SB0();
    }

    // ---- epilogue: row = bm*256 + mh*128 + wm*64 + mf*16 + fq*4 + r
    //               col = bn*256 + nh*128 + wn*32 + nf*16 + fm
    #pragma unroll
    for (int mh = 0; mh < 2; ++mh)
        #pragma unroll
        for (int nh = 0; nh < 2; ++nh)
            #pragma unroll
            for (int nf = 0; nf < 2; ++nf) {
                const int col = bn * 256 + nh * 128 + wn * 32 + nf * 16 + fm;
                const float bj = bias[col];
                #pragma unroll
                for (int mf = 0; mf < 4; ++mf) {
                    const int row0 = bm * 256 + mh * 128 + wm * 64 + mf * 16 + fq * 4;
                    #pragma unroll
                    for (int r = 0; r < 4; ++r) {
                        float v = acc[mh][nh][mf][nf][r] + bj;
                        if (RELU) v = fmaxf(v, 0.f);
                        size_t off = (size_t)(row0 + r) * ldy + col;
                        if (ADDRES) v += bf2f(res[off]);
                        Y[off] = __float2bfloat16(v);
                    }
                }
            }
}

// ---------------------------------------------------------------------------
// MFMA attention over the BATCH axis. qkvb bf16 rows stride QKVM: [Q|K|V].
// Block = one (s',h), 4 waves; wave w owns score rows 16w..16w+15.
// Output bf16 -> aob (stride DSZ). grid = schunk*HN.
// ---------------------------------------------------------------------------
__global__ __launch_bounds__(256) void attn_kernel(
    const __hip_bfloat16* __restrict__ qkvb, __hip_bfloat16* __restrict__ aob)
{
    __shared__ __align__(16) unsigned short Vt[64][72];      // Vt[d][c] = V[c][d]
    __shared__ __align__(16) unsigned short Ps[4][16][72];   // per-wave P rows
    const int t    = threadIdx.x;
    const int wv   = t >> 6;
    const int lane = t & 63;
    const int fm   = lane & 15;
    const int fq   = lane >> 4;
    const int sp   = blockIdx.x / HN;
    const int h    = blockIdx.x % HN;
    const unsigned short* qg =
        (const unsigned short*)qkvb + (size_t)sp * BBATCH * QKVM + h * HDIM;

    // ---- stage V transposed: thread (c=lane, d0=wv*16) reads V[c][d0..d0+15]
    {
        const int c = lane, d0 = wv * 16;
        const unsigned short* vrow = qg + 2 * DSZ + (size_t)c * QKVM + d0;
        bf16x8 v0 = *(const bf16x8*)vrow;
        bf16x8 v1 = *(const bf16x8*)(vrow + 8);
        #pragma unroll
        for (int i = 0; i < 8; ++i) {
            Vt[d0 + i][c]     = (unsigned short)v0[i];
            Vt[d0 + 8 + i][c] = (unsigned short)v1[i];
        }
    }

    // ---- Q A-frags (own 16 rows) and K B-frags (all 64 cols), direct global
    const unsigned short* qrow = qg + (size_t)(wv * 16 + fm) * QKVM + fq * 8;
    bf16x8 af0 = *(const bf16x8*)qrow;
    bf16x8 af1 = *(const bf16x8*)(qrow + 32);
    bf16x8 bk0[4], bk1[4];
    #pragma unroll
    for (int jt = 0; jt < 4; ++jt) {
        const unsigned short* krow = qg + DSZ + (size_t)(jt * 16 + fm) * QKVM + fq * 8;
        bk0[jt] = *(const bf16x8*)krow;
        bk1[jt] = *(const bf16x8*)(krow + 32);
    }

    // ---- scores: 16x64 per wave, fp32 acc
    floatx4 sc[4];
    #pragma unroll
    for (int jt = 0; jt < 4; ++jt) sc[jt] = (floatx4){0.f, 0.f, 0.f, 0.f};
    #pragma unroll
    for (int jt = 0; jt < 4; ++jt) {
        sc[jt] = __builtin_amdgcn_mfma_f32_16x16x32_bf16(af0, bk0[jt], sc[jt], 0, 0, 0);
        sc[jt] = __builtin_amdgcn_mfma_f32_16x16x32_bf16(af1, bk1[jt], sc[jt], 0, 0, 0);
    }
    #pragma unroll
    for (int jt = 0; jt < 4; ++jt)
        #pragma unroll
        for (int r = 0; r < 4; ++r) sc[jt][r] *= 0.125f;

    // ---- softmax per row (row = fq*4+r, spread over 16 lanes x 4 jt)
    float pr[4][4];
    #pragma unroll
    for (int r = 0; r < 4; ++r) {
        float m = fmaxf(fmaxf(sc[0][r], sc[1][r]), fmaxf(sc[2][r], sc[3][r]));
        #pragma unroll
        for (int msk = 1; msk < 16; msk <<= 1) m = fmaxf(m, __shfl_xor(m, msk, 64));
        float s = 0.f;
        #pragma unroll
        for (int jt = 0; jt < 4; ++jt) { pr[jt][r] = __expf(sc[jt][r] - m); s += pr[jt][r]; }
        #pragma unroll
        for (int msk = 1; msk < 16; msk <<= 1) s += __shfl_xor(s, msk, 64);
        float inv = 1.f / s;
        #pragma unroll
        for (int jt = 0; jt < 4; ++jt) pr[jt][r] *= inv;
    }

    // ---- P -> LDS (C-layout -> A-layout round trip), bf16
    #pragma unroll
    for (int jt = 0; jt < 4; ++jt)
        #pragma unroll
        for (int r = 0; r < 4; ++r)
            Ps[wv][fq * 4 + r][jt * 16 + fm] = f2bf_raw(pr[jt][r]);

    __syncthreads();   // Vt (cross-wave) ready; Ps is wave-local

    // ---- PV: A = P (own rows), B = Vt
    bf16x8 ap0 = *(const bf16x8*)&Ps[wv][fm][fq * 8];
    bf16x8 ap1 = *(const bf16x8*)&Ps[wv][fm][32 + fq * 8];
    floatx4 ov[4];
    #pragma unroll
    for (int jt = 0; jt < 4; ++jt) ov[jt] = (floatx4){0.f, 0.f, 0.f, 0.f};
    #pragma unroll
    for (int jt = 0; jt < 4; ++jt) {
        bf16x8 bv0 = *(const bf16x8*)&Vt[jt * 16 + fm][fq * 8];
        bf16x8 bv1 = *(const bf16x8*)&Vt[jt * 16 + fm][32 + fq * 8];
        ov[jt] = __builtin_amdgcn_mfma_f32_16x16x32_bf16(ap0, bv0, ov[jt], 0, 0, 0);
        ov[jt] = __builtin_amdgcn_mfma_f32_16x16x32_bf16(ap1, bv1, ov[jt], 0, 0, 0);
    }

    // ---- write O bf16: row b = 16wv + 4fq + r, col d = jt*16+fm
    __hip_bfloat16* obase = aob + ((size_t)sp * BBATCH + wv * 16 + fq * 4) * DSZ + h * HDIM;
    #pragma unroll
    for (int jt = 0; jt < 4; ++jt)
        #pragma unroll
        for (int r = 0; r < 4; ++r)
            obase[(size_t)r * DSZ + jt * 16 + fm] = __float2bfloat16(ov[jt][r]);
}

// ---------------------------------------------------------------------------
// LayerNorm: src bf16 -> dst bf16 (separate buffers), fp32 stats.
// ---------------------------------------------------------------------------
__device__ __forceinline__ float block_sum256(float vsum, volatile float* red) {
    #pragma unroll
    for (int off = 32; off > 0; off >>= 1) vsum += __shfl_down(vsum, off, 64);
    if ((threadIdx.x & 63) == 0) red[threadIdx.x >> 6] = vsum;
    __syncthreads();
    return red[0] + red[1] + red[2] + red[3];
}

__global__ __launch_bounds__(256) void ln_kernel(
    const __hip_bfloat16* __restrict__ src, __hip_bfloat16* __restrict__ dst,
    const float* __restrict__ g, const float* __restrict__ be)
{
    __shared__ float red1[4];
    __shared__ float red2[4];
    const int n = blockIdx.x;
    const int t = threadIdx.x;
    const __hip_bfloat16* row = src + (size_t)n * DSZ;
    __hip_bfloat16* orow = dst + (size_t)n * DSZ;
    float v0 = bf2f(row[t]), v1 = bf2f(row[t + 256]), v2 = bf2f(row[t + 512]);
    float total = block_sum256(v0 + v1 + v2, red1);
    float mean = total * (1.0f / DSZ);
    float d0 = v0 - mean, d1 = v1 - mean, d2 = v2 - mean;
    __syncthreads();
    float var = block_sum256(d0 * d0 + d1 * d1 + d2 * d2, red2) * (1.0f / DSZ);
    float rstd = rsqrtf(var + 1e-5f);
    orow[t]       = __float2bfloat16(d0 * rstd * g[t]       + be[t]);
    orow[t + 256] = __float2bfloat16(d1 * rstd * g[t + 256] + be[t + 256]);
    orow[t + 512] = __float2bfloat16(d2 * rstd * g[t + 512] + be[t + 512]);
}

// ---------------------------------------------------------------------------
__global__ __launch_bounds__(256) void meanS_kernel(
    const __hip_bfloat16* __restrict__ x, float* __restrict__ xm)
{
    int idx = blockIdx.x * 256 + threadIdx.x;   // over B*D, d fastest
    int b = idx / DSZ, d = idx % DSZ;
    float acc = 0.f;
    for (int s = 0; s < SSEQ; ++s)
        acc += bf2f(x[((size_t)s * BBATCH + b) * DSZ + d]);
    xm[idx] = acc * (1.0f / SSEQ);
}

__global__ __launch_bounds__(128) void fc_kernel(
    const float* __restrict__ xm, const float* __restrict__ fcW,
    const float* __restrict__ fcb, const float* __restrict__ fcA,
    const float* __restrict__ fcBm, float* __restrict__ out)
{
    int t = threadIdx.x;
    if (t >= BBATCH * CN) return;
    int b = t / CN, c = t % CN;
    float acc = fcb[c];
    float lora[RR];
    #pragma unroll
    for (int r = 0; r < RR; ++r) lora[r] = 0.f;
    for (int d = 0; d < DSZ; ++d) {
        float xv = xm[b * DSZ + d];
        acc += xv * fcW[c * DSZ + d];
        #pragma unroll
        for (int r = 0; r < RR; ++r) lora[r] += xv * fcA[r * DSZ + d];
    }
    float lo = 0.f;
    #pragma unroll
    for (int r = 0; r < RR; ++r) lo += lora[r] * fcBm[c * RR + r];
    out[b * CN + c] = acc + SCALEF * lo;
}

// ---------------------------------------------------------------------------
extern "C" void kernel_launch(void* const* d_in, const int* in_sizes, int n_in,
                              void* d_out, int out_size, void* d_ws, size_t ws_size,
                              hipStream_t stream) {
    const int*   tokens = (const int*)  d_in[0];
    const float* embW   = (const float*)d_in[1];
    const float* embA   = (const float*)d_in[2];
    const float* embB   = (const float*)d_in[3];
    const float* Wq = (const float*)d_in[4],  *bq = (const float*)d_in[5],
               * Aq = (const float*)d_in[6],  *Bq = (const float*)d_in[7];
    const float* Wk = (const float*)d_in[8],  *bk = (const float*)d_in[9],
               * Ak = (const float*)d_in[10], *Bk = (const float*)d_in[11];
    const float* Wv = (const float*)d_in[12], *bv = (const float*)d_in[13],
               * Av = (const float*)d_in[14], *Bv = (const float*)d_in[15];
    const float* Wo = (const float*)d_in[16], *bo = (const float*)d_in[17],
               * Ao = (const float*)d_in[18], *Bo = (const float*)d_in[19];
    const float* W1 = (const float*)d_in[20], *b1 = (const float*)d_in[21],
               * A1 = (const float*)d_in[22], *B1 = (const float*)d_in[23];
    const float* W2 = (const float*)d_in[24], *b2 = (const float*)d_in[25],
               * A2 = (const float*)d_in[26], *B2 = (const float*)d_in[27];
    const float* g1 = (const float*)d_in[28], *be1 = (const float*)d_in[29];
    const float* g2 = (const float*)d_in[30], *be2 = (const float*)d_in[31];
    const float* fcW = (const float*)d_in[32], *fcb = (const float*)d_in[33];
    const float* fcA = (const float*)d_in[34], *fcBm = (const float*)d_in[35];

    const size_t ND = (size_t)NTOK * DSZ;

    // ---- workspace layout (float units; all sections multiple of 4) ------
    const size_t X_F    = ND / 2;                       // bf16 x (LN out / residual base)
    const size_t XT_F   = ND / 2;                       // bf16 xt (pre-LN sum)
    const size_t WQKV_F = (size_t)QKVM * DSZ / 2;
    const size_t WO_F   = (size_t)DSZ * DSZ / 2;
    const size_t WF1_F  = (size_t)HIDSZ * DSZ / 2;
    const size_t WF2_F  = (size_t)DSZ * HIDSZ / 2;
    const size_t BQKV_F = 2304;
    const size_t XM_F   = (size_t)BBATCH * DSZ;
    const size_t fixedF = X_F + XT_F + WQKV_F + WO_F + WF1_F + WF2_F + BQKV_F + XM_F;
    const size_t availF = ws_size / 4;

    int schunk = 2;
    const int cand[6] = {512, 256, 128, 64, 32, 16};
    for (int i = 0; i < 6; ++i) {
        // per-chunk: bf16 qkv (Nc*2304) + bf16 aob (Nc*768) == bf16 h (Nc*3072)
        size_t chunkF = (size_t)cand[i] * BBATCH * (HIDSZ / 2);
        if (fixedF + chunkF <= availF) { schunk = cand[i]; break; }
    }
    const int Nc = schunk * BBATCH;
    const int nchunk = SSEQ / schunk;

    float* p = (float*)d_ws;
    __hip_bfloat16* x  = (__hip_bfloat16*)p;     p += X_F;
    __hip_bfloat16* xt = (__hip_bfloat16*)p;     p += XT_F;
    __hip_bfloat16* wqkvb = (__hip_bfloat16*)p;  p += WQKV_F;
    __hip_bfloat16* wob   = (__hip_bfloat16*)p;  p += WO_F;
    __hip_bfloat16* wf1b  = (__hip_bfloat16*)p;  p += WF1_F;
    __hip_bfloat16* wf2b  = (__hip_bfloat16*)p;  p += WF2_F;
    float* bqkv = p;                             p += BQKV_F;
    float* xm   = p;                             p += XM_F;
    __hip_bfloat16* cb16 = (__hip_bfloat16*)p;   // chunk: qkvb|aob, later h
    __hip_bfloat16* qkvb = cb16;
    __hip_bfloat16* aob  = cb16 + (size_t)Nc * QKVM;
    __hip_bfloat16* hb   = cb16;

    embed_kernel<<<NTOK, 256, 0, stream>>>(tokens, embW, embA, embB, x);

    for (int l = 0; l < NL; ++l) {
        const size_t oDD = (size_t)l * DSZ * DSZ;
        const size_t oDH = (size_t)l * HIDSZ * DSZ;
        const size_t oRD = (size_t)l * RR * DSZ;
        const size_t oRH = (size_t)l * RR * HIDSZ;
        const size_t oDR = (size_t)l * DSZ * RR;
        const size_t oHR = (size_t)l * HIDSZ * RR;

        weff_kernel<<<dim3(3, DSZ), 256, 0, stream>>>(Wq + oDD, Aq + oRD, Bq + oDR, wqkvb, DSZ);
        weff_kernel<<<dim3(3, DSZ), 256, 0, stream>>>(Wk + oDD, Ak + oRD, Bk + oDR, wqkvb + (size_t)DSZ * DSZ, DSZ);
        weff_kernel<<<dim3(3, DSZ), 256, 0, stream>>>(Wv + oDD, Av + oRD, Bv + oDR, wqkvb + (size_t)2 * DSZ * DSZ, DSZ);
        biascat_kernel<<<dim3(3, 3), 256, 0, stream>>>(bq + (size_t)l * DSZ, bk + (size_t)l * DSZ, bv + (size_t)l * DSZ, bqkv);
        weff_kernel<<<dim3(3, DSZ), 256, 0, stream>>>(Wo + oDD, Ao + oRD, Bo + oDR, wob, DSZ);
        weff_kernel<<<dim3(3, HIDSZ), 256, 0, stream>>>(W1 + oDH, A1 + oRD, B1 + oHR, wf1b, DSZ);
        weff_kernel<<<dim3(12, DSZ), 256, 0, stream>>>(W2 + oDH, A2 + oRH, B2 + oDR, wf2b, HIDSZ);

        const float* bo_l = bo + (size_t)l * DSZ;
        const float* b1_l = b1 + (size_t)l * HIDSZ;
        const float* b2_l = b2 + (size_t)l * DSZ;

        for (int c = 0; c < nchunk; ++c) {
            __hip_bfloat16* xc  = x  + (size_t)c * Nc * DSZ;
            __hip_bfloat16* xtc = xt + (size_t)c * Nc * DSZ;

            // QKV stacked: (Nc x 768) @ (2304 x 768)^T -> bf16 qkvb
            mgemm256_kernel<false, false><<<dim3(Nc / BM2, QKVM / BM2), 512, 0, stream>>>(
                xc, wqkvb, bqkv, nullptr, qkvb, DSZ, DSZ, QKVM);

            attn_kernel<<<schunk * HN, 256, 0, stream>>>(qkvb, aob);

            // O-proj + residual(x) -> xt, then LN1: xt -> x
            mgemm256_kernel<false, true><<<dim3(Nc / BM2, DSZ / BM2), 512, 0, stream>>>(
                aob, wob, bo_l, xc, xtc, DSZ, DSZ, DSZ);
            ln_kernel<<<Nc, 256, 0, stream>>>(xtc, xc, g1 + (size_t)l * DSZ, be1 + (size_t)l * DSZ);

            // FF1 (relu) -> bf16 h (qkv/aob dead, reuse chunk buffer)
            mgemm256_kernel<true, false><<<dim3(Nc / BM2, HIDSZ / BM2), 512, 0, stream>>>(
                xc, wf1b, b1_l, nullptr, hb, DSZ, DSZ, HIDSZ);

            // FF2 + residual(x) -> xt, then LN2: xt -> x
            mgemm256_kernel<false, true><<<dim3(Nc / BM2, DSZ / BM2), 512, 0, stream>>>(
                hb, wf2b, b2_l, xc, xtc, HIDSZ, HIDSZ, DSZ);
            ln_kernel<<<Nc, 256, 0, stream>>>(xtc, xc, g2 + (size_t)l * DSZ, be2 + (size_t)l * DSZ);
        }
    }

    meanS_kernel<<<(BBATCH * DSZ) / 256, 256, 0, stream>>>(x, xm);
    fc_kernel<<<1, 128, 0, stream>>>(xm, fcW, fcb, fcA, fcBm, (float*)d_out);
}

// Round 4
// 1740.260 us; speedup vs baseline: 1.2729x; 1.0665x over previous
//
#include <hip/hip_runtime.h>
#include <hip/hip_bf16.h>

#define VSZ   32000
#define DSZ   768
#define HN    12
#define HIDSZ 3072
#define NL    2
#define CN    2
#define RR    8
#define SCALEF 2.0f
#define BBATCH 64
#define SSEQ  512
#define HDIM  64
#define NTOK  (BBATCH*SSEQ)   // 32768
#define QKVM  (3*DSZ)         // 2304 — stacked QKV output width

typedef __attribute__((ext_vector_type(8))) short bf16x8;   // 8 bf16 (4 VGPRs)
typedef __attribute__((ext_vector_type(4))) float floatx4;

__device__ __forceinline__ unsigned short f2bf_raw(float f) {
    __hip_bfloat16 h = __float2bfloat16(f);
    return __builtin_bit_cast(unsigned short, h);
}
__device__ __forceinline__ float bf2f(__hip_bfloat16 h) {
    return __bfloat162float(h);
}

// ---------------------------------------------------------------------------
__device__ __forceinline__ void gload16(const void* g, void* l) {
    __builtin_amdgcn_global_load_lds(
        (const __attribute__((address_space(1))) unsigned int*)g,
        (__attribute__((address_space(3))) unsigned int*)l, 16, 0, 0);
}

// ---------------------------------------------------------------------------
// Embedding -> bf16 x
// ---------------------------------------------------------------------------
__global__ __launch_bounds__(256) void embed_kernel(
    const int* __restrict__ tokens, const float* __restrict__ embW,
    const float* __restrict__ embA, const float* __restrict__ embB,
    __hip_bfloat16* __restrict__ xb)
{
    int n = blockIdx.x;            // n = s*B + b
    int s = n / BBATCH, b = n % BBATCH;
    int tok = tokens[b * SSEQ + s];
    __shared__ float a[RR];
    if (threadIdx.x < RR) a[threadIdx.x] = embA[(size_t)threadIdx.x * VSZ + tok];
    __syncthreads();
    for (int d = threadIdx.x; d < DSZ; d += 256) {
        float val = embW[(size_t)tok * DSZ + d];
        float lo = 0.f;
        #pragma unroll
        for (int r = 0; r < RR; ++r) lo += a[r] * embB[d * RR + r];
        xb[(size_t)n * DSZ + d] = __float2bfloat16(val + SCALEF * lo);
    }
}

// ---------------------------------------------------------------------------
// Effective weight (LoRA folded) -> bf16.  grid = (K/256, M)
// ---------------------------------------------------------------------------
__global__ __launch_bounds__(256) void weff_kernel(
    const float* __restrict__ W, const float* __restrict__ A,
    const float* __restrict__ Bm, __hip_bfloat16* __restrict__ Weff, int K)
{
    int i = blockIdx.x * 256 + threadIdx.x;
    int o = blockIdx.y;
    float acc = W[(size_t)o * K + i];
    #pragma unroll
    for (int r = 0; r < RR; ++r)
        acc += SCALEF * Bm[o * RR + r] * A[(size_t)r * K + i];
    Weff[(size_t)o * K + i] = __float2bfloat16(acc);
}

__global__ __launch_bounds__(256) void biascat_kernel(
    const float* __restrict__ b0, const float* __restrict__ b1v,
    const float* __restrict__ b2v, float* __restrict__ out)
{
    int t = blockIdx.y * 256 + threadIdx.x;   // 0..767
    const float* src = (blockIdx.x == 0) ? b0 : (blockIdx.x == 1) ? b1v : b2v;
    out[blockIdx.x * DSZ + t] = src[t];
}

// ---------------------------------------------------------------------------
// 256x256 bf16 MFMA GEMM, 4 phases / 4 barriers per K-step (was 8 barriers).
// Y[n,m] = bf16( X@W^T + bias (+ res) ), optional relu.
// BK=64, 512 thr = 8 waves (2M x 4N). Per kt:
//   g1: read af0(Ab h0)+bf0(Bb h0); stage A1(kt+1)->other | lgkm(0); MFMA 00; bar
//   g2: read bf1(Bb h1);            stage A0(kt+2)->same  | lgkm(0); MFMA 01; bar
//   g3: read af1(Ab h1);            stage B0(kt+2)->same  | lgkm(0); MFMA 10; bar
//   g4:                              stage B1(kt+2)->same | MFMA 11;
//       vmcnt(6|0); bar
// Hazard ledger (all verified):
//  - each staged-over region's reads retire at a per-wave lgkm(0) that
//    precedes a barrier that precedes the overwriting stage issue;
//  - vmcnt(6) before barrier D leaves exactly {A0,B0,B1}(kt+1) in flight ->
//    tile kt+1 A1..B1 fully landed before any wave's g1(kt+1) reads (the
//    vmcnt->barrier pair gives the cross-wave guarantee).
// LDS: 2 dbuf x 32KB x {A,B} = 128 KB, XOR-swizzled (pre-swizzled global src
// + swizzled ds_read). Raw s_barrier only; sched_barrier(0) fences.
// Grid: bn-fastest + bijective XCD chunking.
// ---------------------------------------------------------------------------
#define BM2  256
#define BK2  64
#define ABUF (BM2*BK2)   // 16384 shorts = 32 KB

#define SB0() __builtin_amdgcn_sched_barrier(0)

__device__ __forceinline__ void stage_half(
    const unsigned short* __restrict__ g, unsigned short* l,
    int h, int ld, int k0, int t, int sk)
{
    #pragma unroll
    for (int it = 0; it < 2; ++it) {
        int rl = it * 64 + (t >> 3);
        gload16(g + (size_t)(h * 128 + rl) * ld + k0 + sk,
                l + (size_t)(h * 1024 + it * 512 + t) * 8);
    }
}

template<bool RELU, bool ADDRES>
__device__ __forceinline__ void mgemm_body(
    const __hip_bfloat16* __restrict__ X, const __hip_bfloat16* __restrict__ W,
    const float* __restrict__ bias, const __hip_bfloat16* __restrict__ res,
    __hip_bfloat16* __restrict__ Y, int K, int ldx, int ldy)
{
    __shared__ __align__(16) unsigned short As[2 * ABUF];   // 64 KB
    __shared__ __align__(16) unsigned short Bs[2 * ABUF];   // 64 KB

    const int t    = threadIdx.x;
    const int wv   = t >> 6;
    const int lane = t & 63;
    const int fm   = lane & 15;
    const int fq   = lane >> 4;
    const int wm   = wv >> 2;   // 0..1
    const int wn   = wv & 3;    // 0..3

    // T1: XCD-bijective block swizzle (8 XCDs), then bn-fastest decode
    const int nbx = gridDim.x;   // M blocks
    const int nby = gridDim.y;   // N blocks
    int lin = blockIdx.y * nbx + blockIdx.x;
    {
        const int nwg = nbx * nby;
        int q = nwg >> 3, r = nwg & 7;
        int xcd = lin & 7, idx = lin >> 3;
        lin = (xcd < r ? xcd * (q + 1) : r * (q + 1) + (xcd - r) * q) + idx;
    }
    const int bn = lin % nby;    // N fastest: consecutive blocks share X panel
    const int bm = lin / nby;

    const unsigned short* Xg = (const unsigned short*)X + (size_t)bm * 256 * ldx;
    const unsigned short* Wg = (const unsigned short*)W + (size_t)bn * 256 * K;
    const int sk = ((t & 7) ^ ((t >> 3) & 7)) * 8;   // staging swizzle (elems)
    const int nt = K / BK2;

    floatx4 acc[2][2][4][2];
    #pragma unroll
    for (int a = 0; a < 2; ++a)
        #pragma unroll
        for (int b = 0; b < 2; ++b)
            #pragma unroll
            for (int c = 0; c < 4; ++c)
                #pragma unroll
                for (int d = 0; d < 2; ++d)
                    acc[a][b][c][d] = (floatx4){0.f, 0.f, 0.f, 0.f};

    // fragment base offsets (shorts), h0; +8192 for h1, ^32 for k-slice 1
    const int swzg = (fq ^ (fm & 7)) * 8;
    int aoff[4], boff[2];
    #pragma unroll
    for (int mf = 0; mf < 4; ++mf) aoff[mf] = (wm * 64 + mf * 16 + fm) * 64 + swzg;
    #pragma unroll
    for (int nf = 0; nf < 2; ++nf) boff[nf] = (wn * 32 + nf * 16 + fm) * 64 + swzg;

    // ---- prologue: tile0 full (A0,B0,A1,B1) + tile1 (A0,B0,B1) -> vmcnt(6)
    stage_half(Xg, As, 0, ldx, 0, t, sk);
    stage_half(Wg, Bs, 0, K,   0, t, sk);
    stage_half(Xg, As, 1, ldx, 0, t, sk);
    stage_half(Wg, Bs, 1, K,   0, t, sk);
    if (nt > 1) {
        stage_half(Xg, As + ABUF, 0, ldx, BK2, t, sk);
        stage_half(Wg, Bs + ABUF, 0, K,   BK2, t, sk);
        stage_half(Wg, Bs + ABUF, 1, K,   BK2, t, sk);
        asm volatile("s_waitcnt vmcnt(6)" ::: "memory");
    } else {
        asm volatile("s_waitcnt vmcnt(0)" ::: "memory");
    }
    SB0();
    __builtin_amdgcn_s_barrier();
    SB0();

    for (int kt = 0; kt < nt; ++kt) {
        const unsigned short* Ab = As + (kt & 1) * ABUF;
        const unsigned short* Bb = Bs + (kt & 1) * ABUF;
        unsigned short* Aoth  = As + ((kt & 1) ^ 1) * ABUF;
        unsigned short* Asame = (unsigned short*)Ab;
        unsigned short* Bsame = (unsigned short*)Bb;
        const int k1 = (kt + 1) * BK2;
        const int k2 = (kt + 2) * BK2;
        bf16x8 af0[4][2], af1[4][2], bf0[2][2], bf1[2][2];

        // ---- g1: read af0 + bf0 (tile kt, halves 0); stage A1(kt+1)
        #pragma unroll
        for (int mf = 0; mf < 4; ++mf) {
            af0[mf][0] = *(const bf16x8*)&Ab[aoff[mf]];
            af0[mf][1] = *(const bf16x8*)&Ab[aoff[mf] ^ 32];
        }
        #pragma unroll
        for (int nf = 0; nf < 2; ++nf) {
            bf0[nf][0] = *(const bf16x8*)&Bb[boff[nf]];
            bf0[nf][1] = *(const bf16x8*)&Bb[boff[nf] ^ 32];
        }
        SB0();
        if (kt + 1 < nt) stage_half(Xg, Aoth, 1, ldx, k1, t, sk);
        SB0();
        asm volatile("s_waitcnt lgkmcnt(0)" ::: "memory");
        SB0();
        __builtin_amdgcn_s_setprio(1);
        #pragma unroll
        for (int mf = 0; mf < 4; ++mf)
            #pragma unroll
            for (int nf = 0; nf < 2; ++nf) {
                acc[0][0][mf][nf] = __builtin_amdgcn_mfma_f32_16x16x32_bf16(
                    af0[mf][0], bf0[nf][0], acc[0][0][mf][nf], 0, 0, 0);
                acc[0][0][mf][nf] = __builtin_amdgcn_mfma_f32_16x16x32_bf16(
                    af0[mf][1], bf0[nf][1], acc[0][0][mf][nf], 0, 0, 0);
            }
        __builtin_amdgcn_s_setprio(0);
        SB0();
        __builtin_amdgcn_s_barrier();
        SB0();

        // ---- g2: read bf1 (B h1); stage A0(kt+2) (A-h0 reads retired @g1)
        #pragma unroll
        for (int nf = 0; nf < 2; ++nf) {
            bf1[nf][0] = *(const bf16x8*)&Bb[(boff[nf] + 8192)];
            bf1[nf][1] = *(const bf16x8*)&Bb[(boff[nf] + 8192) ^ 32];
        }
        SB0();
        if (kt + 2 < nt) stage_half(Xg, Asame, 0, ldx, k2, t, sk);
        SB0();
        asm volatile("s_waitcnt lgkmcnt(0)" ::: "memory");
        SB0();
        __builtin_amdgcn_s_setprio(1);
        #pragma unroll
        for (int mf = 0; mf < 4; ++mf)
            #pragma unroll
            for (int nf = 0; nf < 2; ++nf) {
                acc[0][1][mf][nf] = __builtin_amdgcn_mfma_f32_16x16x32_bf16(
                    af0[mf][0], bf1[nf][0], acc[0][1][mf][nf], 0, 0, 0);
                acc[0][1][mf][nf] = __builtin_amdgcn_mfma_f32_16x16x32_bf16(
                    af0[mf][1], bf1[nf][1], acc[0][1][mf][nf], 0, 0, 0);
            }
        __builtin_amdgcn_s_setprio(0);
        SB0();
        __builtin_amdgcn_s_barrier();
        SB0();

        // ---- g3: read af1 (A h1); stage B0(kt+2) (B-h0 reads retired @g1)
        #pragma unroll
        for (int mf = 0; mf < 4; ++mf) {
            af1[mf][0] = *(const bf16x8*)&Ab[(aoff[mf] + 8192)];
            af1[mf][1] = *(const bf16x8*)&Ab[(aoff[mf] + 8192) ^ 32];
        }
        SB0();
        if (kt + 2 < nt) stage_half(Wg, Bsame, 0, K, k2, t, sk);
        SB0();
        asm volatile("s_waitcnt lgkmcnt(0)" ::: "memory");
        SB0();
        __builtin_amdgcn_s_setprio(1);
        #pragma unroll
        for (int mf = 0; mf < 4; ++mf)
            #pragma unroll
            for (int nf = 0; nf < 2; ++nf) {
                acc[1][0][mf][nf] = __builtin_amdgcn_mfma_f32_16x16x32_bf16(
                    af1[mf][0], bf0[nf][0], acc[1][0][mf][nf], 0, 0, 0);
                acc[1][0][mf][nf] = __builtin_amdgcn_mfma_f32_16x16x32_bf16(
                    af1[mf][1], bf0[nf][1], acc[1][0][mf][nf], 0, 0, 0);
            }
        __builtin_amdgcn_s_setprio(0);
        SB0();
        __builtin_amdgcn_s_barrier();
        SB0();

        // ---- g4: stage B1(kt+2) (B-h1 reads retired @g2); MFMA 11;
        //      vmcnt(6) leaves {A0,B0,B1}(kt+1) -> tile kt+1 resident, then bar
        if (kt + 2 < nt) stage_half(Wg, Bsame, 1, K, k2, t, sk);
        SB0();
        __builtin_amdgcn_s_setprio(1);
        #pragma unroll
        for (int mf = 0; mf < 4; ++mf)
            #pragma unroll
            for (int nf = 0; nf < 2; ++nf) {
                acc[1][1][mf][nf] = __builtin_amdgcn_mfma_f32_16x16x32_bf16(
                    af1[mf][0], bf1[nf][0], acc[1][1][mf][nf], 0, 0, 0);
                acc[1][1][mf][nf] = __builtin_amdgcn_mfma_f32_16x16x32_bf16(
                    af1[mf][1], bf1[nf][1], acc[1][1][mf][nf], 0, 0, 0);
            }
        __builtin_amdgcn_s_setprio(0);
        SB0();
        if (kt + 2 < nt) {
            asm volatile("s_waitcnt vmcnt(6)" ::: "memory");
        } else if (kt + 1 < nt) {
            asm volatile("s_waitcnt vmcnt(0)" ::: "memory");
        }
        SB0();
        __builtin_amdgcn_s_barrier();
        SB0();
    }

    // ---- epilogue: row = bm*256 + mh*128 + wm*64 + mf*16 + fq*4 + r
    //               col = bn*256 + nh*128 + wn*32 + nf*16 + fm
    #pragma unroll
    for (int mh = 0; mh < 2; ++mh)
        #pragma unroll
        for (int nh = 0; nh < 2; ++nh)
            #pragma unroll
            for (int nf = 0; nf < 2; ++nf) {
                const int col = bn * 256 + nh * 128 + wn * 32 + nf * 16 + fm;
                const float bj = bias[col];
                #pragma unroll
                for (int mf = 0; mf < 4; ++mf) {
                    const int row0 = bm * 256 + mh * 128 + wm * 64 + mf * 16 + fq * 4;
                    #pragma unroll
                    for (int r = 0; r < 4; ++r) {
                        float v = acc[mh][nh][mf][nf][r] + bj;
                        if (RELU) v = fmaxf(v, 0.f);
                        size_t off = (size_t)(row0 + r) * ldy + col;
                        if (ADDRES) v += bf2f(res[off]);
                        Y[off] = __float2bfloat16(v);
                    }
                }
            }
}

// Distinct kernel names per shape (profiling disambiguation)
__global__ __launch_bounds__(512, 2) void gemm_qkv(
    const __hip_bfloat16* __restrict__ X, const __hip_bfloat16* __restrict__ W,
    const float* __restrict__ bias, const __hip_bfloat16* __restrict__ res,
    __hip_bfloat16* __restrict__ Y, int K, int ldx, int ldy)
{ mgemm_body<false, false>(X, W, bias, res, Y, K, ldx, ldy); }

__global__ __launch_bounds__(512, 2) void gemm_oproj(
    const __hip_bfloat16* __restrict__ X, const __hip_bfloat16* __restrict__ W,
    const float* __restrict__ bias, const __hip_bfloat16* __restrict__ res,
    __hip_bfloat16* __restrict__ Y, int K, int ldx, int ldy)
{ mgemm_body<false, true>(X, W, bias, res, Y, K, ldx, ldy); }

__global__ __launch_bounds__(512, 2) void gemm_ff1(
    const __hip_bfloat16* __restrict__ X, const __hip_bfloat16* __restrict__ W,
    const float* __restrict__ bias, const __hip_bfloat16* __restrict__ res,
    __hip_bfloat16* __restrict__ Y, int K, int ldx, int ldy)
{ mgemm_body<true, false>(X, W, bias, res, Y, K, ldx, ldy); }

__global__ __launch_bounds__(512, 2) void gemm_ff2(
    const __hip_bfloat16* __restrict__ X, const __hip_bfloat16* __restrict__ W,
    const float* __restrict__ bias, const __hip_bfloat16* __restrict__ res,
    __hip_bfloat16* __restrict__ Y, int K, int ldx, int ldy)
{ mgemm_body<false, true>(X, W, bias, res, Y, K, ldx, ldy); }

// ---------------------------------------------------------------------------
// MFMA attention over the BATCH axis. qkvb bf16 rows stride QKVM: [Q|K|V].
// Block = one (s',h), 4 waves; wave w owns score rows 16w..16w+15.
// Output bf16 -> aob (stride DSZ). grid = schunk*HN.
// ---------------------------------------------------------------------------
__global__ __launch_bounds__(256) void attn_kernel(
    const __hip_bfloat16* __restrict__ qkvb, __hip_bfloat16* __restrict__ aob)
{
    __shared__ __align__(16) unsigned short Vt[64][72];      // Vt[d][c] = V[c][d]
    __shared__ __align__(16) unsigned short Ps[4][16][72];   // per-wave P rows
    const int t    = threadIdx.x;
    const int wv   = t >> 6;
    const int lane = t & 63;
    const int fm   = lane & 15;
    const int fq   = lane >> 4;
    const int sp   = blockIdx.x / HN;
    const int h    = blockIdx.x % HN;
    const unsigned short* qg =
        (const unsigned short*)qkvb + (size_t)sp * BBATCH * QKVM + h * HDIM;

    // ---- stage V transposed: thread (c=lane, d0=wv*16) reads V[c][d0..d0+15]
    {
        const int c = lane, d0 = wv * 16;
        const unsigned short* vrow = qg + 2 * DSZ + (size_t)c * QKVM + d0;
        bf16x8 v0 = *(const bf16x8*)vrow;
        bf16x8 v1 = *(const bf16x8*)(vrow + 8);
        #pragma unroll
        for (int i = 0; i < 8; ++i) {
            Vt[d0 + i][c]     = (unsigned short)v0[i];
            Vt[d0 + 8 + i][c] = (unsigned short)v1[i];
        }
    }

    // ---- Q A-frags (own 16 rows) and K B-frags (all 64 cols), direct global
    const unsigned short* qrow = qg + (size_t)(wv * 16 + fm) * QKVM + fq * 8;
    bf16x8 af0 = *(const bf16x8*)qrow;
    bf16x8 af1 = *(const bf16x8*)(qrow + 32);
    bf16x8 bk0[4], bk1[4];
    #pragma unroll
    for (int jt = 0; jt < 4; ++jt) {
        const unsigned short* krow = qg + DSZ + (size_t)(jt * 16 + fm) * QKVM + fq * 8;
        bk0[jt] = *(const bf16x8*)krow;
        bk1[jt] = *(const bf16x8*)(krow + 32);
    }

    // ---- scores: 16x64 per wave, fp32 acc
    floatx4 sc[4];
    #pragma unroll
    for (int jt = 0; jt < 4; ++jt) sc[jt] = (floatx4){0.f, 0.f, 0.f, 0.f};
    #pragma unroll
    for (int jt = 0; jt < 4; ++jt) {
        sc[jt] = __builtin_amdgcn_mfma_f32_16x16x32_bf16(af0, bk0[jt], sc[jt], 0, 0, 0);
        sc[jt] = __builtin_amdgcn_mfma_f32_16x16x32_bf16(af1, bk1[jt], sc[jt], 0, 0, 0);
    }
    #pragma unroll
    for (int jt = 0; jt < 4; ++jt)
        #pragma unroll
        for (int r = 0; r < 4; ++r) sc[jt][r] *= 0.125f;

    // ---- softmax per row (row = fq*4+r, spread over 16 lanes x 4 jt)
    float pr[4][4];
    #pragma unroll
    for (int r = 0; r < 4; ++r) {
        float m = fmaxf(fmaxf(sc[0][r], sc[1][r]), fmaxf(sc[2][r], sc[3][r]));
        #pragma unroll
        for (int msk = 1; msk < 16; msk <<= 1) m = fmaxf(m, __shfl_xor(m, msk, 64));
        float s = 0.f;
        #pragma unroll
        for (int jt = 0; jt < 4; ++jt) { pr[jt][r] = __expf(sc[jt][r] - m); s += pr[jt][r]; }
        #pragma unroll
        for (int msk = 1; msk < 16; msk <<= 1) s += __shfl_xor(s, msk, 64);
        float inv = 1.f / s;
        #pragma unroll
        for (int jt = 0; jt < 4; ++jt) pr[jt][r] *= inv;
    }

    // ---- P -> LDS (C-layout -> A-layout round trip), bf16
    #pragma unroll
    for (int jt = 0; jt < 4; ++jt)
        #pragma unroll
        for (int r = 0; r < 4; ++r)
            Ps[wv][fq * 4 + r][jt * 16 + fm] = f2bf_raw(pr[jt][r]);

    __syncthreads();   // Vt (cross-wave) ready; Ps is wave-local

    // ---- PV: A = P (own rows), B = Vt
    bf16x8 ap0 = *(const bf16x8*)&Ps[wv][fm][fq * 8];
    bf16x8 ap1 = *(const bf16x8*)&Ps[wv][fm][32 + fq * 8];
    floatx4 ov[4];
    #pragma unroll
    for (int jt = 0; jt < 4; ++jt) ov[jt] = (floatx4){0.f, 0.f, 0.f, 0.f};
    #pragma unroll
    for (int jt = 0; jt < 4; ++jt) {
        bf16x8 bv0 = *(const bf16x8*)&Vt[jt * 16 + fm][fq * 8];
        bf16x8 bv1 = *(const bf16x8*)&Vt[jt * 16 + fm][32 + fq * 8];
        ov[jt] = __builtin_amdgcn_mfma_f32_16x16x32_bf16(ap0, bv0, ov[jt], 0, 0, 0);
        ov[jt] = __builtin_amdgcn_mfma_f32_16x16x32_bf16(ap1, bv1, ov[jt], 0, 0, 0);
    }

    // ---- write O bf16: row b = 16wv + 4fq + r, col d = jt*16+fm
    __hip_bfloat16* obase = aob + ((size_t)sp * BBATCH + wv * 16 + fq * 4) * DSZ + h * HDIM;
    #pragma unroll
    for (int jt = 0; jt < 4; ++jt)
        #pragma unroll
        for (int r = 0; r < 4; ++r)
            obase[(size_t)r * DSZ + jt * 16 + fm] = __float2bfloat16(ov[jt][r]);
}

// ---------------------------------------------------------------------------
// LayerNorm: src bf16 -> dst bf16 (separate buffers), fp32 stats.
// ---------------------------------------------------------------------------
__device__ __forceinline__ float block_sum256(float vsum, volatile float* red) {
    #pragma unroll
    for (int off = 32; off > 0; off >>= 1) vsum += __shfl_down(vsum, off, 64);
    if ((threadIdx.x & 63) == 0) red[threadIdx.x >> 6] = vsum;
    __syncthreads();
    return red[0] + red[1] + red[2] + red[3];
}

__global__ __launch_bounds__(256) void ln_kernel(
    const __hip_bfloat16* __restrict__ src, __hip_bfloat16* __restrict__ dst,
    const float* __restrict__ g, const float* __restrict__ be)
{
    __shared__ float red1[4];
    __shared__ float red2[4];
    const int n = blockIdx.x;
    const int t = threadIdx.x;
    const __hip_bfloat16* row = src + (size_t)n * DSZ;
    __hip_bfloat16* orow = dst + (size_t)n * DSZ;
    float v0 = bf2f(row[t]), v1 = bf2f(row[t + 256]), v2 = bf2f(row[t + 512]);
    float total = block_sum256(v0 + v1 + v2, red1);
    float mean = total * (1.0f / DSZ);
    float d0 = v0 - mean, d1 = v1 - mean, d2 = v2 - mean;
    __syncthreads();
    float var = block_sum256(d0 * d0 + d1 * d1 + d2 * d2, red2) * (1.0f / DSZ);
    float rstd = rsqrtf(var + 1e-5f);
    orow[t]       = __float2bfloat16(d0 * rstd * g[t]       + be[t]);
    orow[t + 256] = __float2bfloat16(d1 * rstd * g[t + 256] + be[t + 256]);
    orow[t + 512] = __float2bfloat16(d2 * rstd * g[t + 512] + be[t + 512]);
}

// ---------------------------------------------------------------------------
__global__ __launch_bounds__(256) void meanS_kernel(
    const __hip_bfloat16* __restrict__ x, float* __restrict__ xm)
{
    int idx = blockIdx.x * 256 + threadIdx.x;   // over B*D, d fastest
    int b = idx / DSZ, d = idx % DSZ;
    float acc = 0.f;
    for (int s = 0; s < SSEQ; ++s)
        acc += bf2f(x[((size_t)s * BBATCH + b) * DSZ + d]);
    xm[idx] = acc * (1.0f / SSEQ);
}

__global__ __launch_bounds__(128) void fc_kernel(
    const float* __restrict__ xm, const float* __restrict__ fcW,
    const float* __restrict__ fcb, const float* __restrict__ fcA,
    const float* __restrict__ fcBm, float* __restrict__ out)
{
    int t = threadIdx.x;
    if (t >= BBATCH * CN) return;
    int b = t / CN, c = t % CN;
    float acc = fcb[c];
    float lora[RR];
    #pragma unroll
    for (int r = 0; r < RR; ++r) lora[r] = 0.f;
    for (int d = 0; d < DSZ; ++d) {
        float xv = xm[b * DSZ + d];
        acc += xv * fcW[c * DSZ + d];
        #pragma unroll
        for (int r = 0; r < RR; ++r) lora[r] += xv * fcA[r * DSZ + d];
    }
    float lo = 0.f;
    #pragma unroll
    for (int r = 0; r < RR; ++r) lo += lora[r] * fcBm[c * RR + r];
    out[b * CN + c] = acc + SCALEF * lo;
}

// ---------------------------------------------------------------------------
extern "C" void kernel_launch(void* const* d_in, const int* in_sizes, int n_in,
                              void* d_out, int out_size, void* d_ws, size_t ws_size,
                              hipStream_t stream) {
    const int*   tokens = (const int*)  d_in[0];
    const float* embW   = (const float*)d_in[1];
    const float* embA   = (const float*)d_in[2];
    const float* embB   = (const float*)d_in[3];
    const float* Wq = (const float*)d_in[4],  *bq = (const float*)d_in[5],
               * Aq = (const float*)d_in[6],  *Bq = (const float*)d_in[7];
    const float* Wk = (const float*)d_in[8],  *bk = (const float*)d_in[9],
               * Ak = (const float*)d_in[10], *Bk = (const float*)d_in[11];
    const float* Wv = (const float*)d_in[12], *bv = (const float*)d_in[13],
               * Av = (const float*)d_in[14], *Bv = (const float*)d_in[15];
    const float* Wo = (const float*)d_in[16], *bo = (const float*)d_in[17],
               * Ao = (const float*)d_in[18], *Bo = (const float*)d_in[19];
    const float* W1 = (const float*)d_in[20], *b1 = (const float*)d_in[21],
               * A1 = (const float*)d_in[22], *B1 = (const float*)d_in[23];
    const float* W2 = (const float*)d_in[24], *b2 = (const float*)d_in[25],
               * A2 = (const float*)d_in[26], *B2 = (const float*)d_in[27];
    const float* g1 = (const float*)d_in[28], *be1 = (const float*)d_in[29];
    const float* g2 = (const float*)d_in[30], *be2 = (const float*)d_in[31];
    const float* fcW = (const float*)d_in[32], *fcb = (const float*)d_in[33];
    const float* fcA = (const float*)d_in[34], *fcBm = (const float*)d_in[35];

    const size_t ND = (size_t)NTOK * DSZ;

    // ---- workspace layout (float units; all sections multiple of 4) ------
    const size_t X_F    = ND / 2;                       // bf16 x (LN out / residual base)
    const size_t XT_F   = ND / 2;                       // bf16 xt (pre-LN sum)
    const size_t WQKV_F = (size_t)QKVM * DSZ / 2;
    const size_t WO_F   = (size_t)DSZ * DSZ / 2;
    const size_t WF1_F  = (size_t)HIDSZ * DSZ / 2;
    const size_t WF2_F  = (size_t)DSZ * HIDSZ / 2;
    const size_t BQKV_F = 2304;
    const size_t XM_F   = (size_t)BBATCH * DSZ;
    const size_t fixedF = X_F + XT_F + WQKV_F + WO_F + WF1_F + WF2_F + BQKV_F + XM_F;
    const size_t availF = ws_size / 4;

    int schunk = 2;
    const int cand[6] = {512, 256, 128, 64, 32, 16};
    for (int i = 0; i < 6; ++i) {
        // per-chunk: bf16 qkv (Nc*2304) + bf16 aob (Nc*768) == bf16 h (Nc*3072)
        size_t chunkF = (size_t)cand[i] * BBATCH * (HIDSZ / 2);
        if (fixedF + chunkF <= availF) { schunk = cand[i]; break; }
    }
    const int Nc = schunk * BBATCH;
    const int nchunk = SSEQ / schunk;

    float* p = (float*)d_ws;
    __hip_bfloat16* x  = (__hip_bfloat16*)p;     p += X_F;
    __hip_bfloat16* xt = (__hip_bfloat16*)p;     p += XT_F;
    __hip_bfloat16* wqkvb = (__hip_bfloat16*)p;  p += WQKV_F;
    __hip_bfloat16* wob   = (__hip_bfloat16*)p;  p += WO_F;
    __hip_bfloat16* wf1b  = (__hip_bfloat16*)p;  p += WF1_F;
    __hip_bfloat16* wf2b  = (__hip_bfloat16*)p;  p += WF2_F;
    float* bqkv = p;                             p += BQKV_F;
    float* xm   = p;                             p += XM_F;
    __hip_bfloat16* cb16 = (__hip_bfloat16*)p;   // chunk: qkvb|aob, later h
    __hip_bfloat16* qkvb = cb16;
    __hip_bfloat16* aob  = cb16 + (size_t)Nc * QKVM;
    __hip_bfloat16* hb   = cb16;

    embed_kernel<<<NTOK, 256, 0, stream>>>(tokens, embW, embA, embB, x);

    for (int l = 0; l < NL; ++l) {
        const size_t oDD = (size_t)l * DSZ * DSZ;
        const size_t oDH = (size_t)l * HIDSZ * DSZ;
        const size_t oRD = (size_t)l * RR * DSZ;
        const size_t oRH = (size_t)l * RR * HIDSZ;
        const size_t oDR = (size_t)l * DSZ * RR;
        const size_t oHR = (size_t)l * HIDSZ * RR;

        weff_kernel<<<dim3(3, DSZ), 256, 0, stream>>>(Wq + oDD, Aq + oRD, Bq + oDR, wqkvb, DSZ);
        weff_kernel<<<dim3(3, DSZ), 256, 0, stream>>>(Wk + oDD, Ak + oRD, Bk + oDR, wqkvb + (size_t)DSZ * DSZ, DSZ);
        weff_kernel<<<dim3(3, DSZ), 256, 0, stream>>>(Wv + oDD, Av + oRD, Bv + oDR, wqkvb + (size_t)2 * DSZ * DSZ, DSZ);
        biascat_kernel<<<dim3(3, 3), 256, 0, stream>>>(bq + (size_t)l * DSZ, bk + (size_t)l * DSZ, bv + (size_t)l * DSZ, bqkv);
        weff_kernel<<<dim3(3, DSZ), 256, 0, stream>>>(Wo + oDD, Ao + oRD, Bo + oDR, wob, DSZ);
        weff_kernel<<<dim3(3, HIDSZ), 256, 0, stream>>>(W1 + oDH, A1 + oRD, B1 + oHR, wf1b, DSZ);
        weff_kernel<<<dim3(12, DSZ), 256, 0, stream>>>(W2 + oDH, A2 + oRH, B2 + oDR, wf2b, HIDSZ);

        const float* bo_l = bo + (size_t)l * DSZ;
        const float* b1_l = b1 + (size_t)l * HIDSZ;
        const float* b2_l = b2 + (size_t)l * DSZ;

        for (int c = 0; c < nchunk; ++c) {
            __hip_bfloat16* xc  = x  + (size_t)c * Nc * DSZ;
            __hip_bfloat16* xtc = xt + (size_t)c * Nc * DSZ;

            // QKV stacked: (Nc x 768) @ (2304 x 768)^T -> bf16 qkvb
            gemm_qkv<<<dim3(Nc / BM2, QKVM / BM2), 512, 0, stream>>>(
                xc, wqkvb, bqkv, nullptr, qkvb, DSZ, DSZ, QKVM);

            attn_kernel<<<schunk * HN, 256, 0, stream>>>(qkvb, aob);

            // O-proj + residual(x) -> xt, then LN1: xt -> x
            gemm_oproj<<<dim3(Nc / BM2, DSZ / BM2), 512, 0, stream>>>(
                aob, wob, bo_l, xc, xtc, DSZ, DSZ, DSZ);
            ln_kernel<<<Nc, 256, 0, stream>>>(xtc, xc, g1 + (size_t)l * DSZ, be1 + (size_t)l * DSZ);

            // FF1 -> h, FF2 + residual -> xt, split over M so h stays
            // L3-resident for FF2 (reuse the same hb region per sub-chunk)
            const int nsub = (Nc >= 2 * BM2 && (Nc / 2) % BM2 == 0) ? 2 : 1;
            const int Mh = Nc / nsub;
            for (int sub = 0; sub < nsub; ++sub) {
                const size_t soff = (size_t)sub * Mh * DSZ;
                gemm_ff1<<<dim3(Mh / BM2, HIDSZ / BM2), 512, 0, stream>>>(
                    xc + soff, wf1b, b1_l, nullptr, hb, DSZ, DSZ, HIDSZ);
                gemm_ff2<<<dim3(Mh / BM2, DSZ / BM2), 512, 0, stream>>>(
                    hb, wf2b, b2_l, xc + soff, xtc + soff, HIDSZ, HIDSZ, DSZ);
            }
            ln_kernel<<<Nc, 256, 0, stream>>>(xtc, xc, g2 + (size_t)l * DSZ, be2 + (size_t)l * DSZ);
        }
    }

    meanS_kernel<<<(BBATCH * DSZ) / 256, 256, 0, stream>>>(x, xm);
    fc_kernel<<<1, 128, 0, stream>>>(xm, fcW, fcb, fcA, fcBm, (float*)d_out);
}

// Round 6
// 1735.310 us; speedup vs baseline: 1.2765x; 1.0029x over previous
//
#include <hip/hip_runtime.h>
#include <hip/hip_bf16.h>

#define VSZ   32000
#define DSZ   768
#define HN    12
#define HIDSZ 3072
#define NL    2
#define CN    2
#define RR    8
#define SCALEF 2.0f
#define BBATCH 64
#define SSEQ  512
#define HDIM  64
#define NTOK  (BBATCH*SSEQ)   // 32768
#define QKVM  (3*DSZ)         // 2304 — stacked QKV output width

typedef __attribute__((ext_vector_type(8))) short bf16x8;   // 8 bf16 (4 VGPRs)
typedef __attribute__((ext_vector_type(4))) float floatx4;

__device__ __forceinline__ unsigned short f2bf_raw(float f) {
    __hip_bfloat16 h = __float2bfloat16(f);
    return __builtin_bit_cast(unsigned short, h);
}
__device__ __forceinline__ float bf2f(__hip_bfloat16 h) {
    return __bfloat162float(h);
}

// ---------------------------------------------------------------------------
__device__ __forceinline__ void gload16(const void* g, void* l) {
    __builtin_amdgcn_global_load_lds(
        (const __attribute__((address_space(1))) unsigned int*)g,
        (__attribute__((address_space(3))) unsigned int*)l, 16, 0, 0);
}

// asm ds_read_b128: opaque to the compiler's waitcnt legalizer so it cannot
// insert conservative vmcnt drains ordering these against global_load_lds.
// Ordering is OUR counted lgkmcnt + sched_barrier(0) (rule #18). "memory"
// clobber keeps staging intrinsics from crossing the reads.
__device__ __forceinline__ bf16x8 dsr128(unsigned addr, int off) {
    bf16x8 r;
    asm volatile("ds_read_b128 %0, %1 offset:%2"
                 : "=v"(r) : "v"(addr), "i"(off) : "memory");
    return r;
}

// ---------------------------------------------------------------------------
// Embedding -> bf16 x
// ---------------------------------------------------------------------------
__global__ __launch_bounds__(256) void embed_kernel(
    const int* __restrict__ tokens, const float* __restrict__ embW,
    const float* __restrict__ embA, const float* __restrict__ embB,
    __hip_bfloat16* __restrict__ xb)
{
    int n = blockIdx.x;            // n = s*B + b
    int s = n / BBATCH, b = n % BBATCH;
    int tok = tokens[b * SSEQ + s];
    __shared__ float a[RR];
    if (threadIdx.x < RR) a[threadIdx.x] = embA[(size_t)threadIdx.x * VSZ + tok];
    __syncthreads();
    for (int d = threadIdx.x; d < DSZ; d += 256) {
        float val = embW[(size_t)tok * DSZ + d];
        float lo = 0.f;
        #pragma unroll
        for (int r = 0; r < RR; ++r) lo += a[r] * embB[d * RR + r];
        xb[(size_t)n * DSZ + d] = __float2bfloat16(val + SCALEF * lo);
    }
}

// ---------------------------------------------------------------------------
// Effective weight (LoRA folded) -> bf16.  grid = (K/256, M)
// ---------------------------------------------------------------------------
__global__ __launch_bounds__(256) void weff_kernel(
    const float* __restrict__ W, const float* __restrict__ A,
    const float* __restrict__ Bm, __hip_bfloat16* __restrict__ Weff, int K)
{
    int i = blockIdx.x * 256 + threadIdx.x;
    int o = blockIdx.y;
    float acc = W[(size_t)o * K + i];
    #pragma unroll
    for (int r = 0; r < RR; ++r)
        acc += SCALEF * Bm[o * RR + r] * A[(size_t)r * K + i];
    Weff[(size_t)o * K + i] = __float2bfloat16(acc);
}

__global__ __launch_bounds__(256) void biascat_kernel(
    const float* __restrict__ b0, const float* __restrict__ b1v,
    const float* __restrict__ b2v, float* __restrict__ out)
{
    int t = blockIdx.y * 256 + threadIdx.x;   // 0..767
    const float* src = (blockIdx.x == 0) ? b0 : (blockIdx.x == 1) ? b1v : b2v;
    out[blockIdx.x * DSZ + t] = src[t];
}

// ---------------------------------------------------------------------------
// 256x256 bf16 MFMA GEMM, fully-overlapped schedule, 2 barriers per K-step.
// Y[n,m] = bf16( X@W^T + bias (+ res) ), optional relu.
// BK=64, 512 thr = 8 waves (2M x 4N). Per kt:
//   I1 : issue ALL 24 asm ds_read_b128 (order af0[8],bf0[4],bf1[4],af1[8]);
//        stage A1(kt+1) -> other buf
//   P1 : lgkm(12) -> MFMA af0 x bf0        (reads bf1/af1 still in flight,
//   P2 : lgkm(8)  -> MFMA af0 x bf1         draining under MFMA)
//   P3 : lgkm(0)  -> MFMA af1 x bf0
//   BAR1 (all waves' reads of cur buf retired)
//   stage A0,B0,B1(kt+2) -> cur buf; MFMA af1 x bf1 (P4, overlaps issue)
//   vmcnt(6) [FIFO: leaves exactly the kt+2 loads -> tile kt+1 resident]
//   BAR2
// Tail: at kt=nt-2 vmcnt(0) (the 8 outstanding are all tile nt-1); at nt-1 none.
// k-slice-1 addressing: byte-XOR 64 (NOT +64: swz*16 can set bit 6) — use a
// second base register addr^64; immediate offsets (2048/16384 multiples)
// commute with the XOR since they carry no bits below 2048.
// LDS: 2 dbuf x 32KB x {A,B} = 128 KB, XOR-swizzled both sides.
// Grid: bn-fastest + bijective XCD chunking.
// ---------------------------------------------------------------------------
#define BM2  256
#define BK2  64
#define ABUF (BM2*BK2)   // 16384 shorts = 32 KB

#define SB0() __builtin_amdgcn_sched_barrier(0)

__device__ __forceinline__ void stage_half(
    const unsigned short* __restrict__ g, unsigned short* l,
    int h, int ld, int k0, int t, int sk)
{
    #pragma unroll
    for (int it = 0; it < 2; ++it) {
        int rl = it * 64 + (t >> 3);
        gload16(g + (size_t)(h * 128 + rl) * ld + k0 + sk,
                l + (size_t)(h * 1024 + it * 512 + t) * 8);
    }
}

template<bool RELU, bool ADDRES>
__device__ __forceinline__ void mgemm_body(
    const __hip_bfloat16* __restrict__ X, const __hip_bfloat16* __restrict__ W,
    const float* __restrict__ bias, const __hip_bfloat16* __restrict__ res,
    __hip_bfloat16* __restrict__ Y, int K, int ldx, int ldy)
{
    __shared__ __align__(16) unsigned short As[2 * ABUF];   // 64 KB
    __shared__ __align__(16) unsigned short Bs[2 * ABUF];   // 64 KB

    const int t    = threadIdx.x;
    const int wv   = t >> 6;
    const int lane = t & 63;
    const int fm   = lane & 15;
    const int fq   = lane >> 4;
    const int wm   = wv >> 2;   // 0..1
    const int wn   = wv & 3;    // 0..3

    // T1: XCD-bijective block swizzle (8 XCDs), then bn-fastest decode
    const int nbx = gridDim.x;   // M blocks
    const int nby = gridDim.y;   // N blocks
    int lin = blockIdx.y * nbx + blockIdx.x;
    {
        const int nwg = nbx * nby;
        int q = nwg >> 3, r = nwg & 7;
        int xcd = lin & 7, idx = lin >> 3;
        lin = (xcd < r ? xcd * (q + 1) : r * (q + 1) + (xcd - r) * q) + idx;
    }
    const int bn = lin % nby;    // N fastest: consecutive blocks share X panel
    const int bm = lin / nby;

    const unsigned short* Xg = (const unsigned short*)X + (size_t)bm * 256 * ldx;
    const unsigned short* Wg = (const unsigned short*)W + (size_t)bn * 256 * K;
    const int sk = ((t & 7) ^ ((t >> 3) & 7)) * 8;   // staging swizzle (elems)
    const int nt = K / BK2;

    floatx4 acc[2][2][4][2];
    #pragma unroll
    for (int a = 0; a < 2; ++a)
        #pragma unroll
        for (int b = 0; b < 2; ++b)
            #pragma unroll
            for (int c = 0; c < 4; ++c)
                #pragma unroll
                for (int d = 0; d < 2; ++d)
                    acc[a][b][c][d] = (floatx4){0.f, 0.f, 0.f, 0.f};

    // LDS byte bases for asm reads (AS3 pointers are 32-bit)
    typedef __attribute__((address_space(3))) const unsigned short lds_cus;
    const unsigned asb = (unsigned)(unsigned long long)(lds_cus*)As;
    const unsigned bsb = (unsigned)(unsigned long long)(lds_cus*)Bs;
    const int swzg = (fq ^ (fm & 7)) * 8;
    // per-wave fragment base addrs (bytes); mf/nf step 2048B, h1 +16384B.
    // k-slice 1 = base XOR 64 (separate register; +64 would carry when the
    // swizzle term (fq^(fm&7))*16 >= 64).
    const unsigned aA0 = asb + (unsigned)(((wm * 64 + fm) * 64 + swzg) * 2);
    const unsigned bB0 = bsb + (unsigned)(((wn * 32 + fm) * 64 + swzg) * 2);

    // ---- prologue: tile0 full (A0,B0,A1,B1) + tile1 (A0,B0,B1) -> vmcnt(6)
    stage_half(Xg, As, 0, ldx, 0, t, sk);
    stage_half(Wg, Bs, 0, K,   0, t, sk);
    stage_half(Xg, As, 1, ldx, 0, t, sk);
    stage_half(Wg, Bs, 1, K,   0, t, sk);
    if (nt > 1) {
        stage_half(Xg, As + ABUF, 0, ldx, BK2, t, sk);
        stage_half(Wg, Bs + ABUF, 0, K,   BK2, t, sk);
        stage_half(Wg, Bs + ABUF, 1, K,   BK2, t, sk);
        asm volatile("s_waitcnt vmcnt(6)" ::: "memory");
    } else {
        asm volatile("s_waitcnt vmcnt(0)" ::: "memory");
    }
    SB0();
    __builtin_amdgcn_s_barrier();
    SB0();

    for (int kt = 0; kt < nt; ++kt) {
        const unsigned aBk0 = aA0 + ((kt & 1) << 15);
        const unsigned bBk0 = bB0 + ((kt & 1) << 15);
        const unsigned aBk1 = aBk0 ^ 64u;
        const unsigned bBk1 = bBk0 ^ 64u;
        unsigned short* Aoth  = As + ((kt & 1) ^ 1) * ABUF;
        unsigned short* Asame = As + (kt & 1) * ABUF;
        unsigned short* Bsame = Bs + (kt & 1) * ABUF;
        const int k1 = (kt + 1) * BK2;
        const int k2 = (kt + 2) * BK2;
        bf16x8 af0[4][2], af1[4][2], b0f[2][2], b1f[2][2];

        // ---- I1: issue all 24 reads (order fixes lgkm counts), stage A1(kt+1)
        #pragma unroll
        for (int mf = 0; mf < 4; ++mf) {
            af0[mf][0] = dsr128(aBk0, mf * 2048);
            af0[mf][1] = dsr128(aBk1, mf * 2048);
        }
        #pragma unroll
        for (int nf = 0; nf < 2; ++nf) {
            b0f[nf][0] = dsr128(bBk0, nf * 2048);
            b0f[nf][1] = dsr128(bBk1, nf * 2048);
        }
        #pragma unroll
        for (int nf = 0; nf < 2; ++nf) {
            b1f[nf][0] = dsr128(bBk0, 16384 + nf * 2048);
            b1f[nf][1] = dsr128(bBk1, 16384 + nf * 2048);
        }
        #pragma unroll
        for (int mf = 0; mf < 4; ++mf) {
            af1[mf][0] = dsr128(aBk0, 16384 + mf * 2048);
            af1[mf][1] = dsr128(aBk1, 16384 + mf * 2048);
        }
        SB0();
        if (kt + 1 < nt) stage_half(Xg, Aoth, 1, ldx, k1, t, sk);
        SB0();

        // ---- P1: af0 x b0f (first 12 reads retired)
        asm volatile("s_waitcnt lgkmcnt(12)" ::: "memory");
        SB0();
        __builtin_amdgcn_s_setprio(1);
        #pragma unroll
        for (int mf = 0; mf < 4; ++mf)
            #pragma unroll
            for (int nf = 0; nf < 2; ++nf) {
                acc[0][0][mf][nf] = __builtin_amdgcn_mfma_f32_16x16x32_bf16(
                    af0[mf][0], b0f[nf][0], acc[0][0][mf][nf], 0, 0, 0);
                acc[0][0][mf][nf] = __builtin_amdgcn_mfma_f32_16x16x32_bf16(
                    af0[mf][1], b0f[nf][1], acc[0][0][mf][nf], 0, 0, 0);
            }
        __builtin_amdgcn_s_setprio(0);
        SB0();

        // ---- P2: af0 x b1f
        asm volatile("s_waitcnt lgkmcnt(8)" ::: "memory");
        SB0();
        __builtin_amdgcn_s_setprio(1);
        #pragma unroll
        for (int mf = 0; mf < 4; ++mf)
            #pragma unroll
            for (int nf = 0; nf < 2; ++nf) {
                acc[0][1][mf][nf] = __builtin_amdgcn_mfma_f32_16x16x32_bf16(
                    af0[mf][0], b1f[nf][0], acc[0][1][mf][nf], 0, 0, 0);
                acc[0][1][mf][nf] = __builtin_amdgcn_mfma_f32_16x16x32_bf16(
                    af0[mf][1], b1f[nf][1], acc[0][1][mf][nf], 0, 0, 0);
            }
        __builtin_amdgcn_s_setprio(0);
        SB0();

        // ---- P3: af1 x b0f (all reads retired)
        asm volatile("s_waitcnt lgkmcnt(0)" ::: "memory");
        SB0();
        __builtin_amdgcn_s_setprio(1);
        #pragma unroll
        for (int mf = 0; mf < 4; ++mf)
            #pragma unroll
            for (int nf = 0; nf < 2; ++nf) {
                acc[1][0][mf][nf] = __builtin_amdgcn_mfma_f32_16x16x32_bf16(
                    af1[mf][0], b0f[nf][0], acc[1][0][mf][nf], 0, 0, 0);
                acc[1][0][mf][nf] = __builtin_amdgcn_mfma_f32_16x16x32_bf16(
                    af1[mf][1], b0f[nf][1], acc[1][0][mf][nf], 0, 0, 0);
            }
        __builtin_amdgcn_s_setprio(0);
        SB0();
        __builtin_amdgcn_s_barrier();    // BAR1: cur-buf reads retired block-wide
        SB0();

        // ---- stage kt+2 over cur buf; P4 overlaps the issue
        if (kt + 2 < nt) {
            stage_half(Xg, Asame, 0, ldx, k2, t, sk);
            stage_half(Wg, Bsame, 0, K,   k2, t, sk);
            stage_half(Wg, Bsame, 1, K,   k2, t, sk);
        }
        SB0();
        __builtin_amdgcn_s_setprio(1);
        #pragma unroll
        for (int mf = 0; mf < 4; ++mf)
            #pragma unroll
            for (int nf = 0; nf < 2; ++nf) {
                acc[1][1][mf][nf] = __builtin_amdgcn_mfma_f32_16x16x32_bf16(
                    af1[mf][0], b1f[nf][0], acc[1][1][mf][nf], 0, 0, 0);
                acc[1][1][mf][nf] = __builtin_amdgcn_mfma_f32_16x16x32_bf16(
                    af1[mf][1], b1f[nf][1], acc[1][1][mf][nf], 0, 0, 0);
            }
        __builtin_amdgcn_s_setprio(0);
        SB0();
        if (kt + 2 < nt) {
            asm volatile("s_waitcnt vmcnt(6)" ::: "memory");
        } else if (kt + 1 < nt) {
            asm volatile("s_waitcnt vmcnt(0)" ::: "memory");
        }
        SB0();
        __builtin_amdgcn_s_barrier();    // BAR2: tile kt+1 resident block-wide
        SB0();
    }

    // ---- epilogue: row = bm*256 + mh*128 + wm*64 + mf*16 + fq*4 + r
    //               col = bn*256 + nh*128 + wn*32 + nf*16 + fm
    #pragma unroll
    for (int mh = 0; mh < 2; ++mh)
        #pragma unroll
        for (int nh = 0; nh < 2; ++nh)
            #pragma unroll
            for (int nf = 0; nf < 2; ++nf) {
                const int col = bn * 256 + nh * 128 + wn * 32 + nf * 16 + fm;
                const float bj = bias[col];
                #pragma unroll
                for (int mf = 0; mf < 4; ++mf) {
                    const int row0 = bm * 256 + mh * 128 + wm * 64 + mf * 16 + fq * 4;
                    #pragma unroll
                    for (int r = 0; r < 4; ++r) {
                        float v = acc[mh][nh][mf][nf][r] + bj;
                        if (RELU) v = fmaxf(v, 0.f);
                        size_t off = (size_t)(row0 + r) * ldy + col;
                        if (ADDRES) v += bf2f(res[off]);
                        Y[off] = __float2bfloat16(v);
                    }
                }
            }
}

// Distinct kernel names per shape (profiling disambiguation)
__global__ __launch_bounds__(512, 2) void gemm_qkv(
    const __hip_bfloat16* __restrict__ X, const __hip_bfloat16* __restrict__ W,
    const float* __restrict__ bias, const __hip_bfloat16* __restrict__ res,
    __hip_bfloat16* __restrict__ Y, int K, int ldx, int ldy)
{ mgemm_body<false, false>(X, W, bias, res, Y, K, ldx, ldy); }

__global__ __launch_bounds__(512, 2) void gemm_oproj(
    const __hip_bfloat16* __restrict__ X, const __hip_bfloat16* __restrict__ W,
    const float* __restrict__ bias, const __hip_bfloat16* __restrict__ res,
    __hip_bfloat16* __restrict__ Y, int K, int ldx, int ldy)
{ mgemm_body<false, true>(X, W, bias, res, Y, K, ldx, ldy); }

__global__ __launch_bounds__(512, 2) void gemm_ff1(
    const __hip_bfloat16* __restrict__ X, const __hip_bfloat16* __restrict__ W,
    const float* __restrict__ bias, const __hip_bfloat16* __restrict__ res,
    __hip_bfloat16* __restrict__ Y, int K, int ldx, int ldy)
{ mgemm_body<true, false>(X, W, bias, res, Y, K, ldx, ldy); }

__global__ __launch_bounds__(512, 2) void gemm_ff2(
    const __hip_bfloat16* __restrict__ X, const __hip_bfloat16* __restrict__ W,
    const float* __restrict__ bias, const __hip_bfloat16* __restrict__ res,
    __hip_bfloat16* __restrict__ Y, int K, int ldx, int ldy)
{ mgemm_body<false, true>(X, W, bias, res, Y, K, ldx, ldy); }

// ---------------------------------------------------------------------------
// MFMA attention over the BATCH axis. qkvb bf16 rows stride QKVM: [Q|K|V].
// Block = one (s',h), 4 waves; wave w owns score rows 16w..16w+15.
// Output bf16 -> aob (stride DSZ). grid = schunk*HN.
// ---------------------------------------------------------------------------
__global__ __launch_bounds__(256) void attn_kernel(
    const __hip_bfloat16* __restrict__ qkvb, __hip_bfloat16* __restrict__ aob)
{
    __shared__ __align__(16) unsigned short Vt[64][72];      // Vt[d][c] = V[c][d]
    __shared__ __align__(16) unsigned short Ps[4][16][72];   // per-wave P rows
    const int t    = threadIdx.x;
    const int wv   = t >> 6;
    const int lane = t & 63;
    const int fm   = lane & 15;
    const int fq   = lane >> 4;
    const int sp   = blockIdx.x / HN;
    const int h    = blockIdx.x % HN;
    const unsigned short* qg =
        (const unsigned short*)qkvb + (size_t)sp * BBATCH * QKVM + h * HDIM;

    // ---- stage V transposed: thread (c=lane, d0=wv*16) reads V[c][d0..d0+15]
    {
        const int c = lane, d0 = wv * 16;
        const unsigned short* vrow = qg + 2 * DSZ + (size_t)c * QKVM + d0;
        bf16x8 v0 = *(const bf16x8*)vrow;
        bf16x8 v1 = *(const bf16x8*)(vrow + 8);
        #pragma unroll
        for (int i = 0; i < 8; ++i) {
            Vt[d0 + i][c]     = (unsigned short)v0[i];
            Vt[d0 + 8 + i][c] = (unsigned short)v1[i];
        }
    }

    // ---- Q A-frags (own 16 rows) and K B-frags (all 64 cols), direct global
    const unsigned short* qrow = qg + (size_t)(wv * 16 + fm) * QKVM + fq * 8;
    bf16x8 af0 = *(const bf16x8*)qrow;
    bf16x8 af1 = *(const bf16x8*)(qrow + 32);
    bf16x8 bk0[4], bk1[4];
    #pragma unroll
    for (int jt = 0; jt < 4; ++jt) {
        const unsigned short* krow = qg + DSZ + (size_t)(jt * 16 + fm) * QKVM + fq * 8;
        bk0[jt] = *(const bf16x8*)krow;
        bk1[jt] = *(const bf16x8*)(krow + 32);
    }

    // ---- scores: 16x64 per wave, fp32 acc
    floatx4 sc[4];
    #pragma unroll
    for (int jt = 0; jt < 4; ++jt) sc[jt] = (floatx4){0.f, 0.f, 0.f, 0.f};
    #pragma unroll
    for (int jt = 0; jt < 4; ++jt) {
        sc[jt] = __builtin_amdgcn_mfma_f32_16x16x32_bf16(af0, bk0[jt], sc[jt], 0, 0, 0);
        sc[jt] = __builtin_amdgcn_mfma_f32_16x16x32_bf16(af1, bk1[jt], sc[jt], 0, 0, 0);
    }
    #pragma unroll
    for (int jt = 0; jt < 4; ++jt)
        #pragma unroll
        for (int r = 0; r < 4; ++r) sc[jt][r] *= 0.125f;

    // ---- softmax per row (row = fq*4+r, spread over 16 lanes x 4 jt)
    float pr[4][4];
    #pragma unroll
    for (int r = 0; r < 4; ++r) {
        float m = fmaxf(fmaxf(sc[0][r], sc[1][r]), fmaxf(sc[2][r], sc[3][r]));
        #pragma unroll
        for (int msk = 1; msk < 16; msk <<= 1) m = fmaxf(m, __shfl_xor(m, msk, 64));
        float s = 0.f;
        #pragma unroll
        for (int jt = 0; jt < 4; ++jt) { pr[jt][r] = __expf(sc[jt][r] - m); s += pr[jt][r]; }
        #pragma unroll
        for (int msk = 1; msk < 16; msk <<= 1) s += __shfl_xor(s, msk, 64);
        float inv = 1.f / s;
        #pragma unroll
        for (int jt = 0; jt < 4; ++jt) pr[jt][r] *= inv;
    }

    // ---- P -> LDS (C-layout -> A-layout round trip), bf16
    #pragma unroll
    for (int jt = 0; jt < 4; ++jt)
        #pragma unroll
        for (int r = 0; r < 4; ++r)
            Ps[wv][fq * 4 + r][jt * 16 + fm] = f2bf_raw(pr[jt][r]);

    __syncthreads();   // Vt (cross-wave) ready; Ps is wave-local

    // ---- PV: A = P (own rows), B = Vt
    bf16x8 ap0 = *(const bf16x8*)&Ps[wv][fm][fq * 8];
    bf16x8 ap1 = *(const bf16x8*)&Ps[wv][fm][32 + fq * 8];
    floatx4 ov[4];
    #pragma unroll
    for (int jt = 0; jt < 4; ++jt) ov[jt] = (floatx4){0.f, 0.f, 0.f, 0.f};
    #pragma unroll
    for (int jt = 0; jt < 4; ++jt) {
        bf16x8 bv0 = *(const bf16x8*)&Vt[jt * 16 + fm][fq * 8];
        bf16x8 bv1 = *(const bf16x8*)&Vt[jt * 16 + fm][32 + fq * 8];
        ov[jt] = __builtin_amdgcn_mfma_f32_16x16x32_bf16(ap0, bv0, ov[jt], 0, 0, 0);
        ov[jt] = __builtin_amdgcn_mfma_f32_16x16x32_bf16(ap1, bv1, ov[jt], 0, 0, 0);
    }

    // ---- write O bf16: row b = 16wv + 4fq + r, col d = jt*16+fm
    __hip_bfloat16* obase = aob + ((size_t)sp * BBATCH + wv * 16 + fq * 4) * DSZ + h * HDIM;
    #pragma unroll
    for (int jt = 0; jt < 4; ++jt)
        #pragma unroll
        for (int r = 0; r < 4; ++r)
            obase[(size_t)r * DSZ + jt * 16 + fm] = __float2bfloat16(ov[jt][r]);
}

// ---------------------------------------------------------------------------
// LayerNorm: src bf16 -> dst bf16 (separate buffers), fp32 stats.
// ---------------------------------------------------------------------------
__device__ __forceinline__ float block_sum256(float vsum, volatile float* red) {
    #pragma unroll
    for (int off = 32; off > 0; off >>= 1) vsum += __shfl_down(vsum, off, 64);
    if ((threadIdx.x & 63) == 0) red[threadIdx.x >> 6] = vsum;
    __syncthreads();
    return red[0] + red[1] + red[2] + red[3];
}

__global__ __launch_bounds__(256) void ln_kernel(
    const __hip_bfloat16* __restrict__ src, __hip_bfloat16* __restrict__ dst,
    const float* __restrict__ g, const float* __restrict__ be)
{
    __shared__ float red1[4];
    __shared__ float red2[4];
    const int n = blockIdx.x;
    const int t = threadIdx.x;
    const __hip_bfloat16* row = src + (size_t)n * DSZ;
    __hip_bfloat16* orow = dst + (size_t)n * DSZ;
    float v0 = bf2f(row[t]), v1 = bf2f(row[t + 256]), v2 = bf2f(row[t + 512]);
    float total = block_sum256(v0 + v1 + v2, red1);
    float mean = total * (1.0f / DSZ);
    float d0 = v0 - mean, d1 = v1 - mean, d2 = v2 - mean;
    __syncthreads();
    float var = block_sum256(d0 * d0 + d1 * d1 + d2 * d2, red2) * (1.0f / DSZ);
    float rstd = rsqrtf(var + 1e-5f);
    orow[t]       = __float2bfloat16(d0 * rstd * g[t]       + be[t]);
    orow[t + 256] = __float2bfloat16(d1 * rstd * g[t + 256] + be[t + 256]);
    orow[t + 512] = __float2bfloat16(d2 * rstd * g[t + 512] + be[t + 512]);
}

// ---------------------------------------------------------------------------
__global__ __launch_bounds__(256) void meanS_kernel(
    const __hip_bfloat16* __restrict__ x, float* __restrict__ xm)
{
    int idx = blockIdx.x * 256 + threadIdx.x;   // over B*D, d fastest
    int b = idx / DSZ, d = idx % DSZ;
    float acc = 0.f;
    for (int s = 0; s < SSEQ; ++s)
        acc += bf2f(x[((size_t)s * BBATCH + b) * DSZ + d]);
    xm[idx] = acc * (1.0f / SSEQ);
}

__global__ __launch_bounds__(128) void fc_kernel(
    const float* __restrict__ xm, const float* __restrict__ fcW,
    const float* __restrict__ fcb, const float* __restrict__ fcA,
    const float* __restrict__ fcBm, float* __restrict__ out)
{
    int t = threadIdx.x;
    if (t >= BBATCH * CN) return;
    int b = t / CN, c = t % CN;
    float acc = fcb[c];
    float lora[RR];
    #pragma unroll
    for (int r = 0; r < RR; ++r) lora[r] = 0.f;
    for (int d = 0; d < DSZ; ++d) {
        float xv = xm[b * DSZ + d];
        acc += xv * fcW[c * DSZ + d];
        #pragma unroll
        for (int r = 0; r < RR; ++r) lora[r] += xv * fcA[r * DSZ + d];
    }
    float lo = 0.f;
    #pragma unroll
    for (int r = 0; r < RR; ++r) lo += lora[r] * fcBm[c * RR + r];
    out[b * CN + c] = acc + SCALEF * lo;
}

// ---------------------------------------------------------------------------
extern "C" void kernel_launch(void* const* d_in, const int* in_sizes, int n_in,
                              void* d_out, int out_size, void* d_ws, size_t ws_size,
                              hipStream_t stream) {
    const int*   tokens = (const int*)  d_in[0];
    const float* embW   = (const float*)d_in[1];
    const float* embA   = (const float*)d_in[2];
    const float* embB   = (const float*)d_in[3];
    const float* Wq = (const float*)d_in[4],  *bq = (const float*)d_in[5],
               * Aq = (const float*)d_in[6],  *Bq = (const float*)d_in[7];
    const float* Wk = (const float*)d_in[8],  *bk = (const float*)d_in[9],
               * Ak = (const float*)d_in[10], *Bk = (const float*)d_in[11];
    const float* Wv = (const float*)d_in[12], *bv = (const float*)d_in[13],
               * Av = (const float*)d_in[14], *Bv = (const float*)d_in[15];
    const float* Wo = (const float*)d_in[16], *bo = (const float*)d_in[17],
               * Ao = (const float*)d_in[18], *Bo = (const float*)d_in[19];
    const float* W1 = (const float*)d_in[20], *b1 = (const float*)d_in[21],
               * A1 = (const float*)d_in[22], *B1 = (const float*)d_in[23];
    const float* W2 = (const float*)d_in[24], *b2 = (const float*)d_in[25],
               * A2 = (const float*)d_in[26], *B2 = (const float*)d_in[27];
    const float* g1 = (const float*)d_in[28], *be1 = (const float*)d_in[29];
    const float* g2 = (const float*)d_in[30], *be2 = (const float*)d_in[31];
    const float* fcW = (const float*)d_in[32], *fcb = (const float*)d_in[33];
    const float* fcA = (const float*)d_in[34], *fcBm = (const float*)d_in[35];

    const size_t ND = (size_t)NTOK * DSZ;

    // ---- workspace layout (float units; all sections multiple of 4) ------
    const size_t X_F    = ND / 2;                       // bf16 x (LN out / residual base)
    const size_t XT_F   = ND / 2;                       // bf16 xt (pre-LN sum)
    const size_t WQKV_F = (size_t)QKVM * DSZ / 2;
    const size_t WO_F   = (size_t)DSZ * DSZ / 2;
    const size_t WF1_F  = (size_t)HIDSZ * DSZ / 2;
    const size_t WF2_F  = (size_t)DSZ * HIDSZ / 2;
    const size_t BQKV_F = 2304;
    const size_t XM_F   = (size_t)BBATCH * DSZ;
    const size_t fixedF = X_F + XT_F + WQKV_F + WO_F + WF1_F + WF2_F + BQKV_F + XM_F;
    const size_t availF = ws_size / 4;

    int schunk = 2;
    const int cand[6] = {512, 256, 128, 64, 32, 16};
    for (int i = 0; i < 6; ++i) {
        // per-chunk: bf16 qkv (Nc*2304) + bf16 aob (Nc*768) == bf16 h (Nc*3072)
        size_t chunkF = (size_t)cand[i] * BBATCH * (HIDSZ / 2);
        if (fixedF + chunkF <= availF) { schunk = cand[i]; break; }
    }
    const int Nc = schunk * BBATCH;
    const int nchunk = SSEQ / schunk;

    float* p = (float*)d_ws;
    __hip_bfloat16* x  = (__hip_bfloat16*)p;     p += X_F;
    __hip_bfloat16* xt = (__hip_bfloat16*)p;     p += XT_F;
    __hip_bfloat16* wqkvb = (__hip_bfloat16*)p;  p += WQKV_F;
    __hip_bfloat16* wob   = (__hip_bfloat16*)p;  p += WO_F;
    __hip_bfloat16* wf1b  = (__hip_bfloat16*)p;  p += WF1_F;
    __hip_bfloat16* wf2b  = (__hip_bfloat16*)p;  p += WF2_F;
    float* bqkv = p;                             p += BQKV_F;
    float* xm   = p;                             p += XM_F;
    __hip_bfloat16* cb16 = (__hip_bfloat16*)p;   // chunk: qkvb|aob, later h
    __hip_bfloat16* qkvb = cb16;
    __hip_bfloat16* aob  = cb16 + (size_t)Nc * QKVM;
    __hip_bfloat16* hb   = cb16;

    embed_kernel<<<NTOK, 256, 0, stream>>>(tokens, embW, embA, embB, x);

    for (int l = 0; l < NL; ++l) {
        const size_t oDD = (size_t)l * DSZ * DSZ;
        const size_t oDH = (size_t)l * HIDSZ * DSZ;
        const size_t oRD = (size_t)l * RR * DSZ;
        const size_t oRH = (size_t)l * RR * HIDSZ;
        const size_t oDR = (size_t)l * DSZ * RR;
        const size_t oHR = (size_t)l * HIDSZ * RR;

        weff_kernel<<<dim3(3, DSZ), 256, 0, stream>>>(Wq + oDD, Aq + oRD, Bq + oDR, wqkvb, DSZ);
        weff_kernel<<<dim3(3, DSZ), 256, 0, stream>>>(Wk + oDD, Ak + oRD, Bk + oDR, wqkvb + (size_t)DSZ * DSZ, DSZ);
        weff_kernel<<<dim3(3, DSZ), 256, 0, stream>>>(Wv + oDD, Av + oRD, Bv + oDR, wqkvb + (size_t)2 * DSZ * DSZ, DSZ);
        biascat_kernel<<<dim3(3, 3), 256, 0, stream>>>(bq + (size_t)l * DSZ, bk + (size_t)l * DSZ, bv + (size_t)l * DSZ, bqkv);
        weff_kernel<<<dim3(3, DSZ), 256, 0, stream>>>(Wo + oDD, Ao + oRD, Bo + oDR, wob, DSZ);
        weff_kernel<<<dim3(3, HIDSZ), 256, 0, stream>>>(W1 + oDH, A1 + oRD, B1 + oHR, wf1b, DSZ);
        weff_kernel<<<dim3(12, DSZ), 256, 0, stream>>>(W2 + oDH, A2 + oRH, B2 + oDR, wf2b, HIDSZ);

        const float* bo_l = bo + (size_t)l * DSZ;
        const float* b1_l = b1 + (size_t)l * HIDSZ;
        const float* b2_l = b2 + (size_t)l * DSZ;

        for (int c = 0; c < nchunk; ++c) {
            __hip_bfloat16* xc  = x  + (size_t)c * Nc * DSZ;
            __hip_bfloat16* xtc = xt + (size_t)c * Nc * DSZ;

            // QKV stacked: (Nc x 768) @ (2304 x 768)^T -> bf16 qkvb
            gemm_qkv<<<dim3(Nc / BM2, QKVM / BM2), 512, 0, stream>>>(
                xc, wqkvb, bqkv, nullptr, qkvb, DSZ, DSZ, QKVM);

            attn_kernel<<<schunk * HN, 256, 0, stream>>>(qkvb, aob);

            // O-proj + residual(x) -> xt, then LN1: xt -> x
            gemm_oproj<<<dim3(Nc / BM2, DSZ / BM2), 512, 0, stream>>>(
                aob, wob, bo_l, xc, xtc, DSZ, DSZ, DSZ);
            ln_kernel<<<Nc, 256, 0, stream>>>(xtc, xc, g1 + (size_t)l * DSZ, be1 + (size_t)l * DSZ);

            // FF1 -> h, FF2 + residual -> xt, split over M so h stays
            // L3-resident for FF2 (reuse the same hb region per sub-chunk)
            const int nsub = (Nc >= 2 * BM2 && (Nc / 2) % BM2 == 0) ? 2 : 1;
            const int Mh = Nc / nsub;
            for (int sub = 0; sub < nsub; ++sub) {
                const size_t soff = (size_t)sub * Mh * DSZ;
                gemm_ff1<<<dim3(Mh / BM2, HIDSZ / BM2), 512, 0, stream>>>(
                    xc + soff, wf1b, b1_l, nullptr, hb, DSZ, DSZ, HIDSZ);
                gemm_ff2<<<dim3(Mh / BM2, DSZ / BM2), 512, 0, stream>>>(
                    hb, wf2b, b2_l, xc + soff, xtc + soff, HIDSZ, HIDSZ, DSZ);
            }
            ln_kernel<<<Nc, 256, 0, stream>>>(xtc, xc, g2 + (size_t)l * DSZ, be2 + (size_t)l * DSZ);
        }
    }

    meanS_kernel<<<(BBATCH * DSZ) / 256, 256, 0, stream>>>(x, xm);
    fc_kernel<<<1, 128, 0, stream>>>(xm, fcW, fcb, fcA, fcBm, (float*)d_out);
}